// Round 10
// baseline (624.442 us; speedup 1.0000x reference)
//
#include <hip/hip_runtime.h>
#include <math.h>

// B=64 graphs, A=32 atoms, N=2048 nodes, E=65536 edges, H=512, LAT=256, L=4, DIS=60, EIN=1093
// Weights pre-packed in MFMA-fragment order: tile (kt,nt) of W^T[512][K] at
// ((kt*32+nt)*64+lane)*8 ; lane (lj=l&15, lh=l>>4) holds W^T[nt*16+lj][kt*32+lh*8..+8].
// fd sinusoid fragments precomputed once (layer-invariant). V emitted in f32 D-layout.

typedef short bf16x8 __attribute__((ext_vector_type(8)));
typedef float f32x4 __attribute__((ext_vector_type(4)));

__device__ __forceinline__ float silu_f(float x) {
    float e = __builtin_amdgcn_exp2f(x * -1.44269504088896f);
    return x * __builtin_amdgcn_rcpf(1.0f + e);
}
__device__ __forceinline__ unsigned short f2bf(float x) {
    unsigned int u = __float_as_uint(x);
    u += 0x7fffu + ((u >> 16) & 1u);
    return (unsigned short)(u >> 16);
}
__device__ __forceinline__ unsigned int cvt_pk_bf16(float lo, float hi) {
    unsigned int r;
    asm("v_cvt_pk_bf16_f32 %0, %1, %2" : "=v"(r) : "v"(lo), "v"(hi));
    return r;
}

// ---- workspace layout (float offsets) ----
#define NF_OFF    0
#define UAGG_OFF  (2048*512)
#define VTD_OFF   (2*2048*512)                   // f32 region 64*16384 = 1048576 floats
#define H1_OFF    (VTD_OFF + 64*16384)           // (spare)
#define WBF_OFF   (H1_OFF + 524288)
// bf16 weight region sizes (ushort elements)
#define SZ_INITT (512*768)
#define SZ_UVT   (1024*512)
#define SZ_W1DT  (512*64)
#define SZ_W2T   (512*512)
#define SZ_NW1T  (512*1024)
#define SZ_NW2T  (512*512)
#define SZ_LAYER (SZ_UVT+SZ_W1DT+SZ_W2T+SZ_NW1T+SZ_NW2T)
#define WBF_FLOATS ((SZ_INITT + 4*SZ_LAYER + 1)/2)
#define FDP_OFF   (WBF_OFF + WBF_FLOATS)         // ushort region 1024*8*512

// ---- weight transpose+convert+fragment-pack: f32 [K][512] -> packed bf16 ----
__global__ __launch_bounds__(256) void k_prep(
    const float* __restrict__ Wl, const float* __restrict__ eW1,
    const float* __restrict__ eW2, const float* __restrict__ nW1,
    const float* __restrict__ nW2, unsigned short* __restrict__ wbf)
{
    __shared__ float tile[32][33];
    int bid = blockIdx.x;
    const float* src; int K; unsigned short* dst; int t;
    if (bid < 384) { src = Wl; K = 768; dst = wbf; t = bid; }
    else {
        int b = bid - 384; int l = b / 1568; int j = b - l * 1568;
        const float* e1 = eW1 + (size_t)l * 1093 * 512;
        unsigned short* base = wbf + SZ_INITT + (size_t)l * SZ_LAYER;
        if (j < 256)      { src = e1;                       K = 512;  dst = base;                                   t = j; }
        else if (j < 512) { src = e1 + 512*512;             K = 512;  dst = base + 512*512;                         t = j-256; }
        else if (j < 544) { src = e1 + 1033*512;            K = 60;   dst = base + SZ_UVT;                          t = j-512; }
        else if (j < 800) { src = eW2 + (size_t)l*512*512;  K = 512;  dst = base + SZ_UVT+SZ_W1DT;                  t = j-544; }
        else if (j <1312) { src = nW1 + (size_t)l*1024*512; K = 1024; dst = base + SZ_UVT+SZ_W1DT+SZ_W2T;           t = j-800; }
        else              { src = nW2 + (size_t)l*512*512;  K = 512;  dst = base + SZ_UVT+SZ_W1DT+SZ_W2T+SZ_NW1T;   t = j-1312; }
    }
    int tr = t >> 4, tc = t & 15;
    int k0 = tr * 32, nn0 = tc * 32;
    {
        int r8 = threadIdx.x >> 5, cc = threadIdx.x & 31;
        #pragma unroll
        for (int rr = 0; rr < 4; ++rr) {
            int row = rr*8 + r8;
            int k = k0 + row;
            tile[row][cc] = (k < K) ? src[(size_t)k*512 + nn0 + cc] : 0.f;
        }
    }
    __syncthreads();
    int nt_loc = threadIdx.x >> 7;
    int l = (threadIdx.x >> 1) & 63;
    int jh = threadIdx.x & 1;
    int lj = l & 15, lh = l >> 4;
    float v0 = tile[lh*8 + jh*4 + 0][nt_loc*16 + lj];
    float v1 = tile[lh*8 + jh*4 + 1][nt_loc*16 + lj];
    float v2 = tile[lh*8 + jh*4 + 2][nt_loc*16 + lj];
    float v3 = tile[lh*8 + jh*4 + 3][nt_loc*16 + lj];
    uint2 pk = { cvt_pk_bf16(v0, v1), cvt_pk_bf16(v2, v3) };
    *(uint2*)&dst[((size_t)(tr*32 + tc*2 + nt_loc)*64 + l)*8 + jh*4] = pk;
}

// fd sinusoid B-fragments, once for all layers: fdP[block][kt*4+mt][lane][8]
__global__ __launch_bounds__(64) void k_fd(const float* __restrict__ frac,
                                           unsigned short* __restrict__ fdP)
{
    int bid = blockIdx.x;
    int n0 = bid * 2, g = n0 >> 5;
    int l = threadIdx.x, lj = l & 15, lh = l >> 4;
    float di[2][2][3];
    #pragma unroll
    for (int h = 0; h < 2; ++h)
        #pragma unroll
        for (int dd = 0; dd < 2; ++dd) {
            int dstn = g*32 + dd*16 + lj;
            #pragma unroll
            for (int comp = 0; comp < 3; ++comp) {
                float d = frac[dstn*3 + comp] - frac[(n0+h)*3 + comp];
                d -= floorf(d);
                di[h][dd][comp] = d;
            }
        }
    #pragma unroll
    for (int kt = 0; kt < 2; ++kt)
        #pragma unroll
        for (int mt = 0; mt < 4; ++mt) {
            int h = mt >> 1, dd = mt & 1;
            unsigned int w[4];
            #pragma unroll
            for (int p = 0; p < 4; ++p) {
                float vv[2];
                #pragma unroll
                for (int e = 0; e < 2; ++e) {
                    int k = kt*32 + lh*8 + p*2 + e;
                    float val = 0.f;
                    if (k < 60) {
                        int isCos = k >= 30;
                        int dq = k - (isCos ? 30 : 0);
                        int comp = dq >= 20 ? 2 : (dq >= 10 ? 1 : 0);
                        int f = dq - comp*10;
                        float u = di[h][dd][comp] * (float)f;
                        u -= floorf(u);
                        val = isCos ? __builtin_amdgcn_cosf(u) : __builtin_amdgcn_sinf(u);
                    }
                    vv[e] = val;
                }
                w[p] = cvt_pk_bf16(vv[0], vv[1]);
            }
            uint4 pk = { w[0], w[1], w[2], w[3] };
            *(uint4*)&fdP[(((size_t)bid*8 + kt*4 + mt)*64 + l)*8] = pk;
        }
}

// nf0 = concat(emb,t)@Wl + bl : 16 rows x 256 cols per block, 256 blocks
__global__ __launch_bounds__(256) void k_init(
    const float* __restrict__ tvec, const float* __restrict__ emb,
    const unsigned short* __restrict__ WT, const float* __restrict__ bl,
    const int* __restrict__ atom_types, float* __restrict__ nf)
{
    __shared__ __align__(16) unsigned short cat_s[16*768];
    int n0 = (blockIdx.x >> 1) * 16, half = blockIdx.x & 1, tid = threadIdx.x;
    for (int idx = tid; idx < 16*192; idx += 256) {
        int m = idx / 192, q = idx - m * 192;
        int k4 = q * 4, n = n0 + m;
        float4 v;
        if (k4 < 512) v = *(const float4*)&emb[(size_t)(atom_types[n]-1)*512 + k4];
        else          v = *(const float4*)&tvec[(size_t)(n>>5)*256 + (k4-512)];
        uint2 pk = { cvt_pk_bf16(v.x, v.y), cvt_pk_bf16(v.z, v.w) };
        *(uint2*)&cat_s[m*768 + (k4 ^ ((m&7)<<3))] = pk;
    }
    __syncthreads();
    int w = tid >> 6, l = tid & 63, lj = l & 15, lh = l >> 4;
    f32x4 acc[4];
    #pragma unroll
    for (int nt = 0; nt < 4; ++nt) acc[nt] = (f32x4){0.f,0.f,0.f,0.f};
    for (int kt = 0; kt < 24; ++kt) {
        int k = kt*32 + lh*8;
        bf16x8 a = *(const bf16x8*)&cat_s[lj*768 + (k ^ ((lj&7)<<3))];
        #pragma unroll
        for (int nt = 0; nt < 4; ++nt) {
            bf16x8 b = *(const bf16x8*)&WT[(((size_t)kt*32 + half*16 + w*4 + nt)*64 + l)*8];
            acc[nt] = __builtin_amdgcn_mfma_f32_16x16x32_bf16(a, b, acc[nt], 0, 0, 0);
        }
    }
    #pragma unroll
    for (int nt = 0; nt < 4; ++nt) {
        int c = half*256 + w*64 + nt*16 + lj;
        float bv = bl[c];
        #pragma unroll
        for (int r = 0; r < 4; ++r)
            nf[(size_t)(n0 + lh*4 + r)*512 + c] = acc[nt][r] + bv;
    }
}

// layer-0 only. half0: U' = nf@W1a + latip@W1c + b1; half1: VTD f32 D-layout
__global__ __launch_bounds__(256) void k_uv(
    const float* __restrict__ nf, const unsigned short* __restrict__ WT,
    const float* __restrict__ lat, const float* __restrict__ W1c,
    const float* __restrict__ b1, float* __restrict__ Up,
    float* __restrict__ VTD)
{
    __shared__ __align__(16) unsigned short a_s[16*512];
    int n0 = (blockIdx.x >> 1) * 16, half = blockIdx.x & 1;
    int g = n0 >> 5, tid = threadIdx.x;
    for (int idx = tid; idx < 16*128; idx += 256) {
        int m = idx >> 7, q = idx & 127;
        int k4 = q * 4;
        float4 v = *(const float4*)&nf[(size_t)(n0+m)*512 + k4];
        uint2 pk = { cvt_pk_bf16(v.x, v.y), cvt_pk_bf16(v.z, v.w) };
        *(uint2*)&a_s[m*512 + (k4 ^ ((m&7)<<3))] = pk;
    }
    __syncthreads();
    int w = tid >> 6, l = tid & 63, lj = l & 15, lh = l >> 4;
    const unsigned short* Wh = WT + (size_t)half*512*512;
    f32x4 acc[8];
    #pragma unroll
    for (int nt = 0; nt < 8; ++nt) acc[nt] = (f32x4){0.f,0.f,0.f,0.f};
    for (int kt = 0; kt < 16; ++kt) {
        int k = kt*32 + lh*8;
        bf16x8 a = *(const bf16x8*)&a_s[lj*512 + (k ^ ((lj&7)<<3))];
        #pragma unroll
        for (int nt = 0; nt < 8; ++nt) {
            bf16x8 b = *(const bf16x8*)&Wh[(((size_t)kt*32 + w*8 + nt)*64 + l)*8];
            acc[nt] = __builtin_amdgcn_mfma_f32_16x16x32_bf16(a, b, acc[nt], 0, 0, 0);
        }
    }
    if (half == 0) {
        float L[9], lip[9];
        #pragma unroll
        for (int i = 0; i < 9; ++i) L[i] = lat[g*9 + i];
        #pragma unroll
        for (int i = 0; i < 3; ++i)
            #pragma unroll
            for (int kk = 0; kk < 3; ++kk)
                lip[i*3+kk] = L[i*3]*L[kk*3] + L[i*3+1]*L[kk*3+1] + L[i*3+2]*L[kk*3+2];
        #pragma unroll
        for (int nt = 0; nt < 8; ++nt) {
            int c = w*128 + nt*16 + lj;
            float p3 = b1[c];
            #pragma unroll
            for (int t9 = 0; t9 < 9; ++t9) p3 += lip[t9] * W1c[t9*512 + c];
            #pragma unroll
            for (int r = 0; r < 4; ++r)
                Up[(size_t)(n0 + lh*4 + r)*512 + c] = acc[nt][r] + p3;
        }
    } else {
        int dd = (n0 & 31) >> 4;
        #pragma unroll
        for (int nt = 0; nt < 8; ++nt) {
            int ct = w*8 + nt;
            #pragma unroll
            for (int rr = 0; rr < 4; ++rr)
                VTD[(size_t)g*16384 + ct*512 + dd*256 + (lh*4+rr)*16 + lj] = acc[nt][rr];
        }
    }
}

// fused edge pipeline: 2 src nodes/block (M=64), 512 threads (8 waves), grid 1024.
__global__ __launch_bounds__(512) void k_edge(
    const float* __restrict__ Up, const float* __restrict__ VTD,
    const unsigned short* __restrict__ fdP,
    const unsigned short* __restrict__ W1dT,
    const unsigned short* __restrict__ W2T, const float* __restrict__ b2,
    float* __restrict__ agg)
{
    __shared__ __align__(16) unsigned short ef1_s[64*512];
    int n0 = blockIdx.x * 2, g = n0 >> 5, tid = threadIdx.x;
    int wid = tid >> 6, l = tid & 63, lj = l & 15, lh = l >> 4;

    // ---------------- stage 1 ----------------
    {
        bf16x8 fdf[2][4];
        #pragma unroll
        for (int kt = 0; kt < 2; ++kt)
            #pragma unroll
            for (int mt = 0; mt < 4; ++mt)
                fdf[kt][mt] = *(const bf16x8*)&fdP[(((size_t)blockIdx.x*8 + kt*4 + mt)*64 + l)*8];

        #pragma unroll
        for (int q = 0; q < 4; ++q) {
            int ct = wid*4 + q;
            f32x4 a1[4];
            #pragma unroll
            for (int mt = 0; mt < 4; ++mt)
                a1[mt] = *(const f32x4*)&VTD[(size_t)g*16384 + ct*512 + (mt&1)*256 + lj*16 + lh*4];
            #pragma unroll
            for (int kt = 0; kt < 2; ++kt) {
                bf16x8 wf = *(const bf16x8*)&W1dT[(((size_t)kt*32 + ct)*64 + l)*8];
                #pragma unroll
                for (int mt = 0; mt < 4; ++mt)
                    a1[mt] = __builtin_amdgcn_mfma_f32_16x16x32_bf16(wf, fdf[kt][mt], a1[mt], 0, 0, 0);
            }
            int c0 = wid*64 + q*16 + lh*4;
            float4 bs0 = *(const float4*)&Up[(size_t)n0*512 + c0];
            float4 bs1 = *(const float4*)&Up[(size_t)(n0+1)*512 + c0];
            #pragma unroll
            for (int mt = 0; mt < 4; ++mt) {
                float4 bb = (mt >> 1) ? bs1 : bs0;
                int m = mt*16 + lj;
                float x0 = silu_f(a1[mt][0] + bb.x);
                float x1 = silu_f(a1[mt][1] + bb.y);
                float x2 = silu_f(a1[mt][2] + bb.z);
                float x3 = silu_f(a1[mt][3] + bb.w);
                uint2 pk = { cvt_pk_bf16(x0, x1), cvt_pk_bf16(x2, x3) };
                *(uint2*)&ef1_s[m*512 + (c0 ^ ((m&7)<<3))] = pk;
            }
        }
    }
    __syncthreads();

    // ---------------- stage 2 (barrier-free) ----------------
    f32x4 acc2[4][4];
    #pragma unroll
    for (int mt = 0; mt < 4; ++mt)
        #pragma unroll
        for (int nt = 0; nt < 4; ++nt) acc2[mt][nt] = (f32x4){0.f,0.f,0.f,0.f};

    for (int kt = 0; kt < 16; ++kt) {
        int k = kt*32 + lh*8;
        bf16x8 af[4];
        #pragma unroll
        for (int mt = 0; mt < 4; ++mt) {
            int m = mt*16 + lj;
            af[mt] = *(const bf16x8*)&ef1_s[m*512 + (k ^ ((m&7)<<3))];
        }
        __builtin_amdgcn_s_setprio(1);
        #pragma unroll
        for (int nt = 0; nt < 4; ++nt) {
            bf16x8 bfr = *(const bf16x8*)&W2T[(((size_t)kt*32 + wid*4 + nt)*64 + l)*8];
            #pragma unroll
            for (int mt = 0; mt < 4; ++mt)
                acc2[mt][nt] = __builtin_amdgcn_mfma_f32_16x16x32_bf16(af[mt], bfr, acc2[mt][nt], 0, 0, 0);
        }
        __builtin_amdgcn_s_setprio(0);
    }

    // epilogue: silu + per-node column mean
    #pragma unroll
    for (int nt = 0; nt < 4; ++nt) {
        int cc = wid*64 + nt*16 + lj;
        float bv = b2[cc];
        float s0 = 0.f, s1 = 0.f;
        #pragma unroll
        for (int mt = 0; mt < 4; ++mt)
            #pragma unroll
            for (int r = 0; r < 4; ++r) {
                float x = silu_f(acc2[mt][nt][r] + bv);
                if (mt < 2) s0 += x; else s1 += x;
            }
        s0 += __shfl_xor(s0, 16); s0 += __shfl_xor(s0, 32);
        s1 += __shfl_xor(s1, 16); s1 += __shfl_xor(s1, 32);
        if (lh == 0) {
            agg[(size_t)n0*512 + cc]     = s0 * (1.0f/32.0f);
            agg[(size_t)(n0+1)*512 + cc] = s1 * (1.0f/32.0f);
        }
    }
}

// fused node block + next-layer uv: 16 rows/block, 128 blocks.
//   nf += silu(silu([nf,agg]@nW1+b1)@nW2+b2)  then (do_uv):
//   U'[next] = nf@W1a + latip@W1c + b1e ; VTD[next] = f32 D-layout of nf@W1b
__global__ __launch_bounds__(256) void k_node(
    float* __restrict__ nf, const float* __restrict__ agg,
    const unsigned short* __restrict__ W1T, const float* __restrict__ b1,
    const unsigned short* __restrict__ W2T, const float* __restrict__ b2,
    const unsigned short* __restrict__ uvT, const float* __restrict__ lat,
    const float* __restrict__ W1c, const float* __restrict__ b1e,
    float* __restrict__ Up, float* __restrict__ VTD, int do_uv)
{
    __shared__ __align__(16) unsigned short nin_s[16*1024];  // then nf_new bf16 [16*512]
    __shared__ __align__(16) unsigned short h1_s[16*512];
    int n0 = blockIdx.x * 16, tid = threadIdx.x;
    int g = n0 >> 5;
    for (int idx = tid; idx < 16*256; idx += 256) {
        int m = idx >> 8, q = idx & 255;
        int k4 = q * 4;
        float4 v = (k4 < 512) ? *(const float4*)&nf[(size_t)(n0+m)*512 + k4]
                              : *(const float4*)&agg[(size_t)(n0+m)*512 + (k4-512)];
        uint2 pk = { cvt_pk_bf16(v.x, v.y), cvt_pk_bf16(v.z, v.w) };
        *(uint2*)&nin_s[m*1024 + (k4 ^ ((m&7)<<3))] = pk;
    }
    __syncthreads();
    int w = tid >> 6, l = tid & 63, lj = l & 15, lh = l >> 4;
    // GEMM1: [16,1024]@[1024,512]
    {
        f32x4 acc[8];
        #pragma unroll
        for (int nt = 0; nt < 8; ++nt) acc[nt] = (f32x4){0.f,0.f,0.f,0.f};
        for (int kt = 0; kt < 32; ++kt) {
            int k = kt*32 + lh*8;
            bf16x8 a = *(const bf16x8*)&nin_s[lj*1024 + (k ^ ((lj&7)<<3))];
            #pragma unroll
            for (int nt = 0; nt < 8; ++nt) {
                bf16x8 b = *(const bf16x8*)&W1T[(((size_t)kt*32 + w*8 + nt)*64 + l)*8];
                acc[nt] = __builtin_amdgcn_mfma_f32_16x16x32_bf16(a, b, acc[nt], 0, 0, 0);
            }
        }
        #pragma unroll
        for (int nt = 0; nt < 8; ++nt) {
            int c = w*128 + nt*16 + lj;
            float bv = b1[c];
            #pragma unroll
            for (int r = 0; r < 4; ++r) {
                int m = lh*4 + r;
                h1_s[m*512 + (c ^ ((m&7)<<3))] = f2bf(silu_f(acc[nt][r] + bv));
            }
        }
    }
    __syncthreads();
    // GEMM2: [16,512]@[512,512]; residual into nf; nf_new bf16 -> nin_s (front 16KB)
    {
        f32x4 acc[8];
        #pragma unroll
        for (int nt = 0; nt < 8; ++nt) acc[nt] = (f32x4){0.f,0.f,0.f,0.f};
        for (int kt = 0; kt < 16; ++kt) {
            int k = kt*32 + lh*8;
            bf16x8 a = *(const bf16x8*)&h1_s[lj*512 + (k ^ ((lj&7)<<3))];
            #pragma unroll
            for (int nt = 0; nt < 8; ++nt) {
                bf16x8 b = *(const bf16x8*)&W2T[(((size_t)kt*32 + w*8 + nt)*64 + l)*8];
                acc[nt] = __builtin_amdgcn_mfma_f32_16x16x32_bf16(a, b, acc[nt], 0, 0, 0);
            }
        }
        #pragma unroll
        for (int nt = 0; nt < 8; ++nt) {
            int c = w*128 + nt*16 + lj;
            float bv = b2[c];
            #pragma unroll
            for (int r = 0; r < 4; ++r) {
                int m = lh*4 + r;
                size_t o = (size_t)(n0 + m)*512 + c;
                float v = nf[o] + silu_f(acc[nt][r] + bv);
                nf[o] = v;
                if (do_uv) nin_s[m*512 + (c ^ ((m&7)<<3))] = f2bf(v);
            }
        }
    }
    if (!do_uv) return;
    __syncthreads();
    // UV GEMM: [16,512]@[512,1024] from nf_new in nin_s
    f32x4 acc[16];
    #pragma unroll
    for (int nt = 0; nt < 16; ++nt) acc[nt] = (f32x4){0.f,0.f,0.f,0.f};
    for (int kt = 0; kt < 16; ++kt) {
        int k = kt*32 + lh*8;
        bf16x8 a = *(const bf16x8*)&nin_s[lj*512 + (k ^ ((lj&7)<<3))];
        #pragma unroll
        for (int nt = 0; nt < 16; ++nt) {
            int ct = w*16 + nt;    // 0..63 across waves
            const unsigned short* bp = (ct < 32)
                ? &uvT[(((size_t)kt*32 + ct)*64 + l)*8]
                : &uvT[512*512 + (((size_t)kt*32 + (ct-32))*64 + l)*8];
            bf16x8 b = *(const bf16x8*)bp;
            acc[nt] = __builtin_amdgcn_mfma_f32_16x16x32_bf16(a, b, acc[nt], 0, 0, 0);
        }
    }
    if (w < 2) {
        float L[9], lip[9];
        #pragma unroll
        for (int i = 0; i < 9; ++i) L[i] = lat[g*9 + i];
        #pragma unroll
        for (int i = 0; i < 3; ++i)
            #pragma unroll
            for (int kk = 0; kk < 3; ++kk)
                lip[i*3+kk] = L[i*3]*L[kk*3] + L[i*3+1]*L[kk*3+1] + L[i*3+2]*L[kk*3+2];
        #pragma unroll
        for (int nt = 0; nt < 16; ++nt) {
            int c = w*256 + nt*16 + lj;
            float p3 = b1e[c];
            #pragma unroll
            for (int t9 = 0; t9 < 9; ++t9) p3 += lip[t9] * W1c[t9*512 + c];
            #pragma unroll
            for (int r = 0; r < 4; ++r)
                Up[(size_t)(n0 + lh*4 + r)*512 + c] = acc[nt][r] + p3;
        }
    } else {
        int dd = (n0 & 31) >> 4;
        #pragma unroll
        for (int nt = 0; nt < 16; ++nt) {
            int cc = (w-2)*256 + nt*16 + lj;
            int ct = cc >> 4;
            #pragma unroll
            for (int rr = 0; rr < 4; ++rr)
                VTD[(size_t)g*16384 + ct*512 + dd*256 + (lh*4+rr)*16 + lj] = acc[nt][rr];
        }
    }
}

// coord_out: 64 blocks x 256 thr
__global__ __launch_bounds__(256) void k_coord(const float* __restrict__ nf,
                                               const float* __restrict__ cW,
                                               float* __restrict__ out) {
    int b = blockIdx.x, t = threadIdx.x;
    int nl = t >> 3, s = t & 7;
    int n = b*32 + nl;
    const float* row = nf + (size_t)n*512 + s*64;
    float p0 = 0.f, p1 = 0.f, p2 = 0.f;
    #pragma unroll
    for (int k4 = 0; k4 < 64; k4 += 4) {
        float4 v = *(const float4*)&row[k4];
        int kg = s*64 + k4;
        p0 += v.x*cW[(kg+0)*3+0] + v.y*cW[(kg+1)*3+0] + v.z*cW[(kg+2)*3+0] + v.w*cW[(kg+3)*3+0];
        p1 += v.x*cW[(kg+0)*3+1] + v.y*cW[(kg+1)*3+1] + v.z*cW[(kg+2)*3+1] + v.w*cW[(kg+3)*3+1];
        p2 += v.x*cW[(kg+0)*3+2] + v.y*cW[(kg+1)*3+2] + v.z*cW[(kg+2)*3+2] + v.w*cW[(kg+3)*3+2];
    }
    p0 += __shfl_xor(p0, 1); p0 += __shfl_xor(p0, 2); p0 += __shfl_xor(p0, 4);
    p1 += __shfl_xor(p1, 1); p1 += __shfl_xor(p1, 2); p1 += __shfl_xor(p1, 4);
    p2 += __shfl_xor(p2, 1); p2 += __shfl_xor(p2, 2); p2 += __shfl_xor(p2, 4);
    if (s == 0) {
        out[576 + n*3 + 0] = p0;
        out[576 + n*3 + 1] = p1;
        out[576 + n*3 + 2] = p2;
    }
}

__global__ __launch_bounds__(256) void k_graph(const float* __restrict__ nf,
                                               const float* __restrict__ lW,
                                               const float* __restrict__ lat,
                                               float* __restrict__ out) {
    __shared__ float gf[512];
    __shared__ float lo9[9];
    int b = blockIdx.x, tid = threadIdx.x;
    float s0 = 0.f, s1 = 0.f;
    for (int r = 0; r < 32; ++r) {
        s0 += nf[(b * 32 + r) * 512 + tid];
        s1 += nf[(b * 32 + r) * 512 + tid + 256];
    }
    gf[tid]       = s0 * (1.f / 32.f);
    gf[tid + 256] = s1 * (1.f / 32.f);
    __syncthreads();
    if (tid < 9) {
        float s = 0.f;
        for (int k = 0; k < 512; ++k) s += gf[k] * lW[k * 9 + tid];
        lo9[tid] = s;
    }
    __syncthreads();
    if (tid < 9) {
        int i = tid / 3, kk = tid - (tid / 3) * 3;
        float s = lo9[i*3+0] * lat[b*9 + 0*3 + kk]
                + lo9[i*3+1] * lat[b*9 + 1*3 + kk]
                + lo9[i*3+2] * lat[b*9 + 2*3 + kk];
        out[b * 9 + tid] = s;
    }
}

extern "C" void kernel_launch(void* const* d_in, const int* in_sizes, int n_in,
                              void* d_out, int out_size, void* d_ws, size_t ws_size,
                              hipStream_t stream)
{
    const float* t    = (const float*)d_in[0];
    const float* frac = (const float*)d_in[1];
    const float* lat  = (const float*)d_in[2];
    const float* emb  = (const float*)d_in[3];
    const float* Wl   = (const float*)d_in[4];
    const float* bl   = (const float*)d_in[5];
    const float* eW1  = (const float*)d_in[6];
    const float* eb1  = (const float*)d_in[7];
    const float* eW2  = (const float*)d_in[8];
    const float* eb2  = (const float*)d_in[9];
    const float* nW1  = (const float*)d_in[10];
    const float* nb1  = (const float*)d_in[11];
    const float* nW2  = (const float*)d_in[12];
    const float* nb2  = (const float*)d_in[13];
    const float* cW   = (const float*)d_in[14];
    const float* lW   = (const float*)d_in[15];
    const int* atom_types = (const int*)d_in[16];

    float* out  = (float*)d_out;
    float* wsf  = (float*)d_ws;
    float* nf   = wsf + NF_OFF;
    float* Uagg = wsf + UAGG_OFF;   // U' during k_edge; agg after (row-exclusive)
    float* VTD  = wsf + VTD_OFF;
    unsigned short* wbf = (unsigned short*)(wsf + WBF_OFF);
    unsigned short* fdP = (unsigned short*)(wsf + FDP_OFF);

    k_prep<<<384 + 4*1568, 256, 0, stream>>>(Wl, eW1, eW2, nW1, nW2, wbf);
    k_fd<<<1024, 64, 0, stream>>>(frac, fdP);
    k_init<<<256, 256, 0, stream>>>(t, emb, wbf, bl, atom_types, nf);
    {   // layer-0 uv
        const unsigned short* uvT0 = wbf + SZ_INITT;
        k_uv<<<256, 256, 0, stream>>>(nf, uvT0, lat,
                                      eW1 + 1024*512, eb1, Uagg, VTD);
    }
    for (int l = 0; l < 4; ++l) {
        const unsigned short* base = wbf + SZ_INITT + (size_t)l * SZ_LAYER;
        const unsigned short* w1dT = base + SZ_UVT;
        const unsigned short* w2T  = w1dT + SZ_W1DT;
        const unsigned short* nw1T = w2T + SZ_W2T;
        const unsigned short* nw2T = nw1T + SZ_NW1T;
        k_edge<<<1024, 512, 0, stream>>>(Uagg, VTD, fdP, w1dT, w2T,
                                         eb2 + l*512, Uagg);
        int ln = (l < 3) ? l + 1 : l;   // next layer's uv params (unused when do_uv=0)
        const unsigned short* uvTn = wbf + SZ_INITT + (size_t)ln * SZ_LAYER;
        k_node<<<128, 256, 0, stream>>>(nf, Uagg,
                                        nw1T, nb1 + l*512, nw2T, nb2 + l*512,
                                        uvTn, lat,
                                        eW1 + (size_t)ln*1093*512 + 1024*512,
                                        eb1 + ln*512,
                                        Uagg, VTD, (l < 3) ? 1 : 0);
    }
    k_coord<<<64, 256, 0, stream>>>(nf, cW, out);
    k_graph<<<64, 256, 0, stream>>>(nf, lW, lat, out);
}

// Round 11
// 386.795 us; speedup vs baseline: 1.6144x; 1.6144x over previous
//
#include <hip/hip_runtime.h>
#include <math.h>

// B=64 graphs, A=32 atoms, N=2048 nodes, E=65536 edges, H=512, LAT=256, L=4, DIS=60, EIN=1093
// Weights pre-packed in MFMA-fragment order: tile (kt,nt) of W^T[512][K] at
// ((kt*32+nt)*64+lane)*8 ; lane (lj=l&15, lh=l>>4) holds W^T[nt*16+lj][kt*32+lh*8..+8].
// fd sinusoid fragments precomputed once (layer-invariant). V emitted in f32 D-layout.
// Node-side kernels run 512 blocks (col-split) — grid size IS the occupancy lever
// (r10 lesson: 128-block fusion = 1 wave/SIMD = 114us of idle machine).

typedef short bf16x8 __attribute__((ext_vector_type(8)));
typedef float f32x4 __attribute__((ext_vector_type(4)));

__device__ __forceinline__ float silu_f(float x) {
    float e = __builtin_amdgcn_exp2f(x * -1.44269504088896f);
    return x * __builtin_amdgcn_rcpf(1.0f + e);
}
__device__ __forceinline__ unsigned short f2bf(float x) {
    unsigned int u = __float_as_uint(x);
    u += 0x7fffu + ((u >> 16) & 1u);
    return (unsigned short)(u >> 16);
}
__device__ __forceinline__ unsigned int cvt_pk_bf16(float lo, float hi) {
    unsigned int r;
    asm("v_cvt_pk_bf16_f32 %0, %1, %2" : "=v"(r) : "v"(lo), "v"(hi));
    return r;
}

// ---- workspace layout (float offsets) ----
#define NF_OFF    0
#define UAGG_OFF  (2048*512)
#define VTD_OFF   (2*2048*512)                   // f32 region 64*16384 = 1048576 floats
#define H1_OFF    (VTD_OFF + 64*16384)           // ushort region 2048*512 = 524288 floats
#define WBF_OFF   (H1_OFF + 524288)
// bf16 weight region sizes (ushort elements)
#define SZ_INITT (512*768)
#define SZ_UVT   (1024*512)
#define SZ_W1DT  (512*64)
#define SZ_W2T   (512*512)
#define SZ_NW1T  (512*1024)
#define SZ_NW2T  (512*512)
#define SZ_LAYER (SZ_UVT+SZ_W1DT+SZ_W2T+SZ_NW1T+SZ_NW2T)
#define WBF_FLOATS ((SZ_INITT + 4*SZ_LAYER + 1)/2)
#define FDP_OFF   (WBF_OFF + WBF_FLOATS)         // ushort region 1024*8*512

// ---- weight transpose+convert+fragment-pack: f32 [K][512] -> packed bf16 ----
__global__ __launch_bounds__(256) void k_prep(
    const float* __restrict__ Wl, const float* __restrict__ eW1,
    const float* __restrict__ eW2, const float* __restrict__ nW1,
    const float* __restrict__ nW2, unsigned short* __restrict__ wbf)
{
    __shared__ float tile[32][33];
    int bid = blockIdx.x;
    const float* src; int K; unsigned short* dst; int t;
    if (bid < 384) { src = Wl; K = 768; dst = wbf; t = bid; }
    else {
        int b = bid - 384; int l = b / 1568; int j = b - l * 1568;
        const float* e1 = eW1 + (size_t)l * 1093 * 512;
        unsigned short* base = wbf + SZ_INITT + (size_t)l * SZ_LAYER;
        if (j < 256)      { src = e1;                       K = 512;  dst = base;                                   t = j; }
        else if (j < 512) { src = e1 + 512*512;             K = 512;  dst = base + 512*512;                         t = j-256; }
        else if (j < 544) { src = e1 + 1033*512;            K = 60;   dst = base + SZ_UVT;                          t = j-512; }
        else if (j < 800) { src = eW2 + (size_t)l*512*512;  K = 512;  dst = base + SZ_UVT+SZ_W1DT;                  t = j-544; }
        else if (j <1312) { src = nW1 + (size_t)l*1024*512; K = 1024; dst = base + SZ_UVT+SZ_W1DT+SZ_W2T;           t = j-800; }
        else              { src = nW2 + (size_t)l*512*512;  K = 512;  dst = base + SZ_UVT+SZ_W1DT+SZ_W2T+SZ_NW1T;   t = j-1312; }
    }
    int tr = t >> 4, tc = t & 15;
    int k0 = tr * 32, nn0 = tc * 32;
    {
        int r8 = threadIdx.x >> 5, cc = threadIdx.x & 31;
        #pragma unroll
        for (int rr = 0; rr < 4; ++rr) {
            int row = rr*8 + r8;
            int k = k0 + row;
            tile[row][cc] = (k < K) ? src[(size_t)k*512 + nn0 + cc] : 0.f;
        }
    }
    __syncthreads();
    int nt_loc = threadIdx.x >> 7;
    int l = (threadIdx.x >> 1) & 63;
    int jh = threadIdx.x & 1;
    int lj = l & 15, lh = l >> 4;
    float v0 = tile[lh*8 + jh*4 + 0][nt_loc*16 + lj];
    float v1 = tile[lh*8 + jh*4 + 1][nt_loc*16 + lj];
    float v2 = tile[lh*8 + jh*4 + 2][nt_loc*16 + lj];
    float v3 = tile[lh*8 + jh*4 + 3][nt_loc*16 + lj];
    uint2 pk = { cvt_pk_bf16(v0, v1), cvt_pk_bf16(v2, v3) };
    *(uint2*)&dst[((size_t)(tr*32 + tc*2 + nt_loc)*64 + l)*8 + jh*4] = pk;
}

// fd sinusoid B-fragments, once for all layers: fdP[block][kt*4+mt][lane][8]
__global__ __launch_bounds__(64) void k_fd(const float* __restrict__ frac,
                                           unsigned short* __restrict__ fdP)
{
    int bid = blockIdx.x;
    int n0 = bid * 2, g = n0 >> 5;
    int l = threadIdx.x, lj = l & 15, lh = l >> 4;
    float di[2][2][3];
    #pragma unroll
    for (int h = 0; h < 2; ++h)
        #pragma unroll
        for (int dd = 0; dd < 2; ++dd) {
            int dstn = g*32 + dd*16 + lj;
            #pragma unroll
            for (int comp = 0; comp < 3; ++comp) {
                float d = frac[dstn*3 + comp] - frac[(n0+h)*3 + comp];
                d -= floorf(d);
                di[h][dd][comp] = d;
            }
        }
    #pragma unroll
    for (int kt = 0; kt < 2; ++kt)
        #pragma unroll
        for (int mt = 0; mt < 4; ++mt) {
            int h = mt >> 1, dd = mt & 1;
            unsigned int w[4];
            #pragma unroll
            for (int p = 0; p < 4; ++p) {
                float vv[2];
                #pragma unroll
                for (int e = 0; e < 2; ++e) {
                    int k = kt*32 + lh*8 + p*2 + e;
                    float val = 0.f;
                    if (k < 60) {
                        int isCos = k >= 30;
                        int dq = k - (isCos ? 30 : 0);
                        int comp = dq >= 20 ? 2 : (dq >= 10 ? 1 : 0);
                        int f = dq - comp*10;
                        float u = di[h][dd][comp] * (float)f;
                        u -= floorf(u);
                        val = isCos ? __builtin_amdgcn_cosf(u) : __builtin_amdgcn_sinf(u);
                    }
                    vv[e] = val;
                }
                w[p] = cvt_pk_bf16(vv[0], vv[1]);
            }
            uint4 pk = { w[0], w[1], w[2], w[3] };
            *(uint4*)&fdP[(((size_t)bid*8 + kt*4 + mt)*64 + l)*8] = pk;
        }
}

// nf0 = concat(emb,t)@Wl + bl : 16 rows x 256 cols per block, 256 blocks
__global__ __launch_bounds__(256) void k_init(
    const float* __restrict__ tvec, const float* __restrict__ emb,
    const unsigned short* __restrict__ WT, const float* __restrict__ bl,
    const int* __restrict__ atom_types, float* __restrict__ nf)
{
    __shared__ __align__(16) unsigned short cat_s[16*768];
    int n0 = (blockIdx.x >> 1) * 16, half = blockIdx.x & 1, tid = threadIdx.x;
    for (int idx = tid; idx < 16*192; idx += 256) {
        int m = idx / 192, q = idx - m * 192;
        int k4 = q * 4, n = n0 + m;
        float4 v;
        if (k4 < 512) v = *(const float4*)&emb[(size_t)(atom_types[n]-1)*512 + k4];
        else          v = *(const float4*)&tvec[(size_t)(n>>5)*256 + (k4-512)];
        uint2 pk = { cvt_pk_bf16(v.x, v.y), cvt_pk_bf16(v.z, v.w) };
        *(uint2*)&cat_s[m*768 + (k4 ^ ((m&7)<<3))] = pk;
    }
    __syncthreads();
    int w = tid >> 6, l = tid & 63, lj = l & 15, lh = l >> 4;
    f32x4 acc[4];
    #pragma unroll
    for (int nt = 0; nt < 4; ++nt) acc[nt] = (f32x4){0.f,0.f,0.f,0.f};
    for (int kt = 0; kt < 24; ++kt) {
        int k = kt*32 + lh*8;
        bf16x8 a = *(const bf16x8*)&cat_s[lj*768 + (k ^ ((lj&7)<<3))];
        #pragma unroll
        for (int nt = 0; nt < 4; ++nt) {
            bf16x8 b = *(const bf16x8*)&WT[(((size_t)kt*32 + half*16 + w*4 + nt)*64 + l)*8];
            acc[nt] = __builtin_amdgcn_mfma_f32_16x16x32_bf16(a, b, acc[nt], 0, 0, 0);
        }
    }
    #pragma unroll
    for (int nt = 0; nt < 4; ++nt) {
        int c = half*256 + w*64 + nt*16 + lj;
        float bv = bl[c];
        #pragma unroll
        for (int r = 0; r < 4; ++r)
            nf[(size_t)(n0 + lh*4 + r)*512 + c] = acc[nt][r] + bv;
    }
}

// 512 blocks: ng = bid>>2 (16 rows), half = (bid>>1)&1 (U'|V), ch = bid&1 (col half).
// half0: U' = nf@W1a + latip@W1c + b1 (f32); half1: VTD f32 D-layout per graph
__global__ __launch_bounds__(256) void k_uv(
    const float* __restrict__ nf, const unsigned short* __restrict__ WT,
    const float* __restrict__ lat, const float* __restrict__ W1c,
    const float* __restrict__ b1, float* __restrict__ Up,
    float* __restrict__ VTD)
{
    __shared__ __align__(16) unsigned short a_s[16*512];
    int ng = blockIdx.x >> 2, half = (blockIdx.x >> 1) & 1, ch = blockIdx.x & 1;
    int n0 = ng * 16, g = n0 >> 5, tid = threadIdx.x;
    for (int idx = tid; idx < 16*128; idx += 256) {
        int m = idx >> 7, q = idx & 127;
        int k4 = q * 4;
        float4 v = *(const float4*)&nf[(size_t)(n0+m)*512 + k4];
        uint2 pk = { cvt_pk_bf16(v.x, v.y), cvt_pk_bf16(v.z, v.w) };
        *(uint2*)&a_s[m*512 + (k4 ^ ((m&7)<<3))] = pk;
    }
    __syncthreads();
    int w = tid >> 6, l = tid & 63, lj = l & 15, lh = l >> 4;
    const unsigned short* Wh = WT + (size_t)half*512*512;
    f32x4 acc[4];
    #pragma unroll
    for (int nt = 0; nt < 4; ++nt) acc[nt] = (f32x4){0.f,0.f,0.f,0.f};
    for (int kt = 0; kt < 16; ++kt) {
        int k = kt*32 + lh*8;
        bf16x8 a = *(const bf16x8*)&a_s[lj*512 + (k ^ ((lj&7)<<3))];
        #pragma unroll
        for (int nt = 0; nt < 4; ++nt) {
            bf16x8 b = *(const bf16x8*)&Wh[(((size_t)kt*32 + ch*16 + w*4 + nt)*64 + l)*8];
            acc[nt] = __builtin_amdgcn_mfma_f32_16x16x32_bf16(a, b, acc[nt], 0, 0, 0);
        }
    }
    if (half == 0) {
        float L[9], lip[9];
        #pragma unroll
        for (int i = 0; i < 9; ++i) L[i] = lat[g*9 + i];
        #pragma unroll
        for (int i = 0; i < 3; ++i)
            #pragma unroll
            for (int kk = 0; kk < 3; ++kk)
                lip[i*3+kk] = L[i*3]*L[kk*3] + L[i*3+1]*L[kk*3+1] + L[i*3+2]*L[kk*3+2];
        #pragma unroll
        for (int nt = 0; nt < 4; ++nt) {
            int c = ch*256 + w*64 + nt*16 + lj;
            float p3 = b1[c];
            #pragma unroll
            for (int t9 = 0; t9 < 9; ++t9) p3 += lip[t9] * W1c[t9*512 + c];
            #pragma unroll
            for (int r = 0; r < 4; ++r)
                Up[(size_t)(n0 + lh*4 + r)*512 + c] = acc[nt][r] + p3;
        }
    } else {
        int dd = (n0 & 31) >> 4;
        #pragma unroll
        for (int nt = 0; nt < 4; ++nt) {
            int ct = ch*16 + w*4 + nt;
            #pragma unroll
            for (int rr = 0; rr < 4; ++rr)
                VTD[(size_t)g*16384 + ct*512 + dd*256 + (lh*4+rr)*16 + lj] = acc[nt][rr];
        }
    }
}

// fused edge pipeline: 2 src nodes/block (M=64), 512 threads (8 waves), grid 1024.
__global__ __launch_bounds__(512) void k_edge(
    const float* __restrict__ Up, const float* __restrict__ VTD,
    const unsigned short* __restrict__ fdP,
    const unsigned short* __restrict__ W1dT,
    const unsigned short* __restrict__ W2T, const float* __restrict__ b2,
    float* __restrict__ agg)
{
    __shared__ __align__(16) unsigned short ef1_s[64*512];
    int n0 = blockIdx.x * 2, g = n0 >> 5, tid = threadIdx.x;
    int wid = tid >> 6, l = tid & 63, lj = l & 15, lh = l >> 4;

    // ---------------- stage 1 ----------------
    {
        bf16x8 fdf[2][4];
        #pragma unroll
        for (int kt = 0; kt < 2; ++kt)
            #pragma unroll
            for (int mt = 0; mt < 4; ++mt)
                fdf[kt][mt] = *(const bf16x8*)&fdP[(((size_t)blockIdx.x*8 + kt*4 + mt)*64 + l)*8];

        #pragma unroll
        for (int q = 0; q < 4; ++q) {
            int ct = wid*4 + q;
            f32x4 a1[4];
            #pragma unroll
            for (int mt = 0; mt < 4; ++mt)
                a1[mt] = *(const f32x4*)&VTD[(size_t)g*16384 + ct*512 + (mt&1)*256 + lj*16 + lh*4];
            #pragma unroll
            for (int kt = 0; kt < 2; ++kt) {
                bf16x8 wf = *(const bf16x8*)&W1dT[(((size_t)kt*32 + ct)*64 + l)*8];
                #pragma unroll
                for (int mt = 0; mt < 4; ++mt)
                    a1[mt] = __builtin_amdgcn_mfma_f32_16x16x32_bf16(wf, fdf[kt][mt], a1[mt], 0, 0, 0);
            }
            int c0 = wid*64 + q*16 + lh*4;
            float4 bs0 = *(const float4*)&Up[(size_t)n0*512 + c0];
            float4 bs1 = *(const float4*)&Up[(size_t)(n0+1)*512 + c0];
            #pragma unroll
            for (int mt = 0; mt < 4; ++mt) {
                float4 bb = (mt >> 1) ? bs1 : bs0;
                int m = mt*16 + lj;
                float x0 = silu_f(a1[mt][0] + bb.x);
                float x1 = silu_f(a1[mt][1] + bb.y);
                float x2 = silu_f(a1[mt][2] + bb.z);
                float x3 = silu_f(a1[mt][3] + bb.w);
                uint2 pk = { cvt_pk_bf16(x0, x1), cvt_pk_bf16(x2, x3) };
                *(uint2*)&ef1_s[m*512 + (c0 ^ ((m&7)<<3))] = pk;
            }
        }
    }
    __syncthreads();

    // ---------------- stage 2 (barrier-free) ----------------
    f32x4 acc2[4][4];
    #pragma unroll
    for (int mt = 0; mt < 4; ++mt)
        #pragma unroll
        for (int nt = 0; nt < 4; ++nt) acc2[mt][nt] = (f32x4){0.f,0.f,0.f,0.f};

    for (int kt = 0; kt < 16; ++kt) {
        int k = kt*32 + lh*8;
        bf16x8 af[4];
        #pragma unroll
        for (int mt = 0; mt < 4; ++mt) {
            int m = mt*16 + lj;
            af[mt] = *(const bf16x8*)&ef1_s[m*512 + (k ^ ((m&7)<<3))];
        }
        __builtin_amdgcn_s_setprio(1);
        #pragma unroll
        for (int nt = 0; nt < 4; ++nt) {
            bf16x8 bfr = *(const bf16x8*)&W2T[(((size_t)kt*32 + wid*4 + nt)*64 + l)*8];
            #pragma unroll
            for (int mt = 0; mt < 4; ++mt)
                acc2[mt][nt] = __builtin_amdgcn_mfma_f32_16x16x32_bf16(af[mt], bfr, acc2[mt][nt], 0, 0, 0);
        }
        __builtin_amdgcn_s_setprio(0);
    }

    // epilogue: silu + per-node column mean
    #pragma unroll
    for (int nt = 0; nt < 4; ++nt) {
        int cc = wid*64 + nt*16 + lj;
        float bv = b2[cc];
        float s0 = 0.f, s1 = 0.f;
        #pragma unroll
        for (int mt = 0; mt < 4; ++mt)
            #pragma unroll
            for (int r = 0; r < 4; ++r) {
                float x = silu_f(acc2[mt][nt][r] + bv);
                if (mt < 2) s0 += x; else s1 += x;
            }
        s0 += __shfl_xor(s0, 16); s0 += __shfl_xor(s0, 32);
        s1 += __shfl_xor(s1, 16); s1 += __shfl_xor(s1, 32);
        if (lh == 0) {
            agg[(size_t)n0*512 + cc]     = s0 * (1.0f/32.0f);
            agg[(size_t)(n0+1)*512 + cc] = s1 * (1.0f/32.0f);
        }
    }
}

// h1 = silu([nf,agg]@nW1 + b1) -> bf16 global ; 16 rows x 128 cols, 512 blocks
__global__ __launch_bounds__(256) void k_node1(
    const float* __restrict__ nf, const float* __restrict__ agg,
    const unsigned short* __restrict__ W1T, const float* __restrict__ b1,
    unsigned short* __restrict__ h1g)
{
    __shared__ __align__(16) unsigned short nin_s[16*1024];
    int ng = blockIdx.x >> 2, cq = blockIdx.x & 3;
    int n0 = ng * 16, tid = threadIdx.x;
    for (int idx = tid; idx < 16*256; idx += 256) {
        int m = idx >> 8, q = idx & 255;
        int k4 = q * 4;
        float4 v = (k4 < 512) ? *(const float4*)&nf[(size_t)(n0+m)*512 + k4]
                              : *(const float4*)&agg[(size_t)(n0+m)*512 + (k4-512)];
        uint2 pk = { cvt_pk_bf16(v.x, v.y), cvt_pk_bf16(v.z, v.w) };
        *(uint2*)&nin_s[m*1024 + (k4 ^ ((m&7)<<3))] = pk;
    }
    __syncthreads();
    int w = tid >> 6, l = tid & 63, lj = l & 15, lh = l >> 4;
    f32x4 acc[2];
    acc[0] = (f32x4){0.f,0.f,0.f,0.f};
    acc[1] = (f32x4){0.f,0.f,0.f,0.f};
    for (int kt = 0; kt < 32; ++kt) {
        int k = kt*32 + lh*8;
        bf16x8 a = *(const bf16x8*)&nin_s[lj*1024 + (k ^ ((lj&7)<<3))];
        #pragma unroll
        for (int nt = 0; nt < 2; ++nt) {
            bf16x8 b = *(const bf16x8*)&W1T[(((size_t)kt*32 + cq*8 + w*2 + nt)*64 + l)*8];
            acc[nt] = __builtin_amdgcn_mfma_f32_16x16x32_bf16(a, b, acc[nt], 0, 0, 0);
        }
    }
    #pragma unroll
    for (int nt = 0; nt < 2; ++nt) {
        int c = cq*128 + w*32 + nt*16 + lj;
        float bv = b1[c];
        #pragma unroll
        for (int r = 0; r < 4; ++r)
            h1g[(size_t)(n0 + lh*4 + r)*512 + c] = f2bf(silu_f(acc[nt][r] + bv));
    }
}

// nf += silu(h1@nW2 + b2) ; 16 rows x 128 cols, 512 blocks
__global__ __launch_bounds__(256) void k_node2(
    float* __restrict__ nf, const unsigned short* __restrict__ h1g,
    const unsigned short* __restrict__ W2T, const float* __restrict__ b2)
{
    __shared__ __align__(16) unsigned short h1_s[16*512];
    int ng = blockIdx.x >> 2, cq = blockIdx.x & 3;
    int n0 = ng * 16, tid = threadIdx.x;
    for (int idx = tid; idx < 16*64; idx += 256) {
        int m = idx >> 6, k8 = (idx & 63) * 8;
        bf16x8 v = *(const bf16x8*)&h1g[(size_t)(n0+m)*512 + k8];
        *(bf16x8*)&h1_s[m*512 + (k8 ^ ((m&7)<<3))] = v;
    }
    __syncthreads();
    int w = tid >> 6, l = tid & 63, lj = l & 15, lh = l >> 4;
    f32x4 acc[2];
    acc[0] = (f32x4){0.f,0.f,0.f,0.f};
    acc[1] = (f32x4){0.f,0.f,0.f,0.f};
    for (int kt = 0; kt < 16; ++kt) {
        int k = kt*32 + lh*8;
        bf16x8 a = *(const bf16x8*)&h1_s[lj*512 + (k ^ ((lj&7)<<3))];
        #pragma unroll
        for (int nt = 0; nt < 2; ++nt) {
            bf16x8 b = *(const bf16x8*)&W2T[(((size_t)kt*32 + cq*8 + w*2 + nt)*64 + l)*8];
            acc[nt] = __builtin_amdgcn_mfma_f32_16x16x32_bf16(a, b, acc[nt], 0, 0, 0);
        }
    }
    #pragma unroll
    for (int nt = 0; nt < 2; ++nt) {
        int c = cq*128 + w*32 + nt*16 + lj;
        float bv = b2[c];
        #pragma unroll
        for (int r = 0; r < 4; ++r) {
            size_t o = (size_t)(n0 + lh*4 + r)*512 + c;
            nf[o] = nf[o] + silu_f(acc[nt][r] + bv);
        }
    }
}

// coord_out: 64 blocks x 256 thr
__global__ __launch_bounds__(256) void k_coord(const float* __restrict__ nf,
                                               const float* __restrict__ cW,
                                               float* __restrict__ out) {
    int b = blockIdx.x, t = threadIdx.x;
    int nl = t >> 3, s = t & 7;
    int n = b*32 + nl;
    const float* row = nf + (size_t)n*512 + s*64;
    float p0 = 0.f, p1 = 0.f, p2 = 0.f;
    #pragma unroll
    for (int k4 = 0; k4 < 64; k4 += 4) {
        float4 v = *(const float4*)&row[k4];
        int kg = s*64 + k4;
        p0 += v.x*cW[(kg+0)*3+0] + v.y*cW[(kg+1)*3+0] + v.z*cW[(kg+2)*3+0] + v.w*cW[(kg+3)*3+0];
        p1 += v.x*cW[(kg+0)*3+1] + v.y*cW[(kg+1)*3+1] + v.z*cW[(kg+2)*3+1] + v.w*cW[(kg+3)*3+1];
        p2 += v.x*cW[(kg+0)*3+2] + v.y*cW[(kg+1)*3+2] + v.z*cW[(kg+2)*3+2] + v.w*cW[(kg+3)*3+2];
    }
    p0 += __shfl_xor(p0, 1); p0 += __shfl_xor(p0, 2); p0 += __shfl_xor(p0, 4);
    p1 += __shfl_xor(p1, 1); p1 += __shfl_xor(p1, 2); p1 += __shfl_xor(p1, 4);
    p2 += __shfl_xor(p2, 1); p2 += __shfl_xor(p2, 2); p2 += __shfl_xor(p2, 4);
    if (s == 0) {
        out[576 + n*3 + 0] = p0;
        out[576 + n*3 + 1] = p1;
        out[576 + n*3 + 2] = p2;
    }
}

__global__ __launch_bounds__(256) void k_graph(const float* __restrict__ nf,
                                               const float* __restrict__ lW,
                                               const float* __restrict__ lat,
                                               float* __restrict__ out) {
    __shared__ float gf[512];
    __shared__ float lo9[9];
    int b = blockIdx.x, tid = threadIdx.x;
    float s0 = 0.f, s1 = 0.f;
    for (int r = 0; r < 32; ++r) {
        s0 += nf[(b * 32 + r) * 512 + tid];
        s1 += nf[(b * 32 + r) * 512 + tid + 256];
    }
    gf[tid]       = s0 * (1.f / 32.f);
    gf[tid + 256] = s1 * (1.f / 32.f);
    __syncthreads();
    if (tid < 9) {
        float s = 0.f;
        for (int k = 0; k < 512; ++k) s += gf[k] * lW[k * 9 + tid];
        lo9[tid] = s;
    }
    __syncthreads();
    if (tid < 9) {
        int i = tid / 3, kk = tid - (tid / 3) * 3;
        float s = lo9[i*3+0] * lat[b*9 + 0*3 + kk]
                + lo9[i*3+1] * lat[b*9 + 1*3 + kk]
                + lo9[i*3+2] * lat[b*9 + 2*3 + kk];
        out[b * 9 + tid] = s;
    }
}

extern "C" void kernel_launch(void* const* d_in, const int* in_sizes, int n_in,
                              void* d_out, int out_size, void* d_ws, size_t ws_size,
                              hipStream_t stream)
{
    const float* t    = (const float*)d_in[0];
    const float* frac = (const float*)d_in[1];
    const float* lat  = (const float*)d_in[2];
    const float* emb  = (const float*)d_in[3];
    const float* Wl   = (const float*)d_in[4];
    const float* bl   = (const float*)d_in[5];
    const float* eW1  = (const float*)d_in[6];
    const float* eb1  = (const float*)d_in[7];
    const float* eW2  = (const float*)d_in[8];
    const float* eb2  = (const float*)d_in[9];
    const float* nW1  = (const float*)d_in[10];
    const float* nb1  = (const float*)d_in[11];
    const float* nW2  = (const float*)d_in[12];
    const float* nb2  = (const float*)d_in[13];
    const float* cW   = (const float*)d_in[14];
    const float* lW   = (const float*)d_in[15];
    const int* atom_types = (const int*)d_in[16];

    float* out  = (float*)d_out;
    float* wsf  = (float*)d_ws;
    float* nf   = wsf + NF_OFF;
    float* Uagg = wsf + UAGG_OFF;   // U' during k_edge; agg after (row-exclusive)
    float* VTD  = wsf + VTD_OFF;
    unsigned short* h1g = (unsigned short*)(wsf + H1_OFF);
    unsigned short* wbf = (unsigned short*)(wsf + WBF_OFF);
    unsigned short* fdP = (unsigned short*)(wsf + FDP_OFF);

    k_prep<<<384 + 4*1568, 256, 0, stream>>>(Wl, eW1, eW2, nW1, nW2, wbf);
    k_fd<<<1024, 64, 0, stream>>>(frac, fdP);
    k_init<<<256, 256, 0, stream>>>(t, emb, wbf, bl, atom_types, nf);
    for (int l = 0; l < 4; ++l) {
        const unsigned short* base = wbf + SZ_INITT + (size_t)l * SZ_LAYER;
        const unsigned short* w1dT = base + SZ_UVT;
        const unsigned short* w2T  = w1dT + SZ_W1DT;
        const unsigned short* nw1T = w2T + SZ_W2T;
        const unsigned short* nw2T = nw1T + SZ_NW1T;
        k_uv<<<512, 256, 0, stream>>>(nf, base, lat,
                                      eW1 + (size_t)l*1093*512 + 1024*512,
                                      eb1 + l*512, Uagg, VTD);
        k_edge<<<1024, 512, 0, stream>>>(Uagg, VTD, fdP, w1dT, w2T,
                                         eb2 + l*512, Uagg);
        k_node1<<<512, 256, 0, stream>>>(nf, Uagg, nw1T, nb1 + l*512, h1g);
        k_node2<<<512, 256, 0, stream>>>(nf, h1g, nw2T, nb2 + l*512);
    }
    k_coord<<<64, 256, 0, stream>>>(nf, cW, out);
    k_graph<<<64, 256, 0, stream>>>(nf, lW, lat, out);
}

// Round 12
// 376.766 us; speedup vs baseline: 1.6574x; 1.0266x over previous
//
#include <hip/hip_runtime.h>
#include <math.h>

// B=64 graphs, A=32 atoms, N=2048 nodes, E=65536 edges, H=512, LAT=256, L=4, DIS=60, EIN=1093
// Weights pre-packed in MFMA-fragment order: tile (kt,nt) of W^T[512][K] at
// ((kt*32+nt)*64+lane)*8 ; lane (lj=l&15, lh=l>>4) holds W^T[nt*16+lj][kt*32+lh*8..+8].
// fd sinusoid fragments precomputed once (layer-invariant). V emitted in f32 D-layout.
// All K-loops software-pipeline the B-fragment global loads (load kt+1 before kt's
// MFMA cluster) — r11 PMC showed VGPR=60 + latency-bound stage2.

typedef short bf16x8 __attribute__((ext_vector_type(8)));
typedef float f32x4 __attribute__((ext_vector_type(4)));

__device__ __forceinline__ float silu_f(float x) {
    float e = __builtin_amdgcn_exp2f(x * -1.44269504088896f);
    return x * __builtin_amdgcn_rcpf(1.0f + e);
}
__device__ __forceinline__ unsigned short f2bf(float x) {
    unsigned int u = __float_as_uint(x);
    u += 0x7fffu + ((u >> 16) & 1u);
    return (unsigned short)(u >> 16);
}
__device__ __forceinline__ unsigned int cvt_pk_bf16(float lo, float hi) {
    unsigned int r;
    asm("v_cvt_pk_bf16_f32 %0, %1, %2" : "=v"(r) : "v"(lo), "v"(hi));
    return r;
}

// ---- workspace layout (float offsets) ----
#define NF_OFF    0
#define UAGG_OFF  (2048*512)
#define VTD_OFF   (2*2048*512)                   // f32 region 64*16384 = 1048576 floats
#define H1_OFF    (VTD_OFF + 64*16384)           // ushort region 2048*512 = 524288 floats
#define WBF_OFF   (H1_OFF + 524288)
// bf16 weight region sizes (ushort elements)
#define SZ_INITT (512*768)
#define SZ_UVT   (1024*512)
#define SZ_W1DT  (512*64)
#define SZ_W2T   (512*512)
#define SZ_NW1T  (512*1024)
#define SZ_NW2T  (512*512)
#define SZ_LAYER (SZ_UVT+SZ_W1DT+SZ_W2T+SZ_NW1T+SZ_NW2T)
#define WBF_FLOATS ((SZ_INITT + 4*SZ_LAYER + 1)/2)
#define FDP_OFF   (WBF_OFF + WBF_FLOATS)         // ushort region 1024*8*512

// ---- weight transpose+convert+fragment-pack: f32 [K][512] -> packed bf16 ----
__global__ __launch_bounds__(256) void k_prep(
    const float* __restrict__ Wl, const float* __restrict__ eW1,
    const float* __restrict__ eW2, const float* __restrict__ nW1,
    const float* __restrict__ nW2, unsigned short* __restrict__ wbf)
{
    __shared__ float tile[32][33];
    int bid = blockIdx.x;
    const float* src; int K; unsigned short* dst; int t;
    if (bid < 384) { src = Wl; K = 768; dst = wbf; t = bid; }
    else {
        int b = bid - 384; int l = b / 1568; int j = b - l * 1568;
        const float* e1 = eW1 + (size_t)l * 1093 * 512;
        unsigned short* base = wbf + SZ_INITT + (size_t)l * SZ_LAYER;
        if (j < 256)      { src = e1;                       K = 512;  dst = base;                                   t = j; }
        else if (j < 512) { src = e1 + 512*512;             K = 512;  dst = base + 512*512;                         t = j-256; }
        else if (j < 544) { src = e1 + 1033*512;            K = 60;   dst = base + SZ_UVT;                          t = j-512; }
        else if (j < 800) { src = eW2 + (size_t)l*512*512;  K = 512;  dst = base + SZ_UVT+SZ_W1DT;                  t = j-544; }
        else if (j <1312) { src = nW1 + (size_t)l*1024*512; K = 1024; dst = base + SZ_UVT+SZ_W1DT+SZ_W2T;           t = j-800; }
        else              { src = nW2 + (size_t)l*512*512;  K = 512;  dst = base + SZ_UVT+SZ_W1DT+SZ_W2T+SZ_NW1T;   t = j-1312; }
    }
    int tr = t >> 4, tc = t & 15;
    int k0 = tr * 32, nn0 = tc * 32;
    {
        int r8 = threadIdx.x >> 5, cc = threadIdx.x & 31;
        #pragma unroll
        for (int rr = 0; rr < 4; ++rr) {
            int row = rr*8 + r8;
            int k = k0 + row;
            tile[row][cc] = (k < K) ? src[(size_t)k*512 + nn0 + cc] : 0.f;
        }
    }
    __syncthreads();
    int nt_loc = threadIdx.x >> 7;
    int l = (threadIdx.x >> 1) & 63;
    int jh = threadIdx.x & 1;
    int lj = l & 15, lh = l >> 4;
    float v0 = tile[lh*8 + jh*4 + 0][nt_loc*16 + lj];
    float v1 = tile[lh*8 + jh*4 + 1][nt_loc*16 + lj];
    float v2 = tile[lh*8 + jh*4 + 2][nt_loc*16 + lj];
    float v3 = tile[lh*8 + jh*4 + 3][nt_loc*16 + lj];
    uint2 pk = { cvt_pk_bf16(v0, v1), cvt_pk_bf16(v2, v3) };
    *(uint2*)&dst[((size_t)(tr*32 + tc*2 + nt_loc)*64 + l)*8 + jh*4] = pk;
}

// fd sinusoid B-fragments, once for all layers: fdP[block][kt*4+mt][lane][8]
__global__ __launch_bounds__(64) void k_fd(const float* __restrict__ frac,
                                           unsigned short* __restrict__ fdP)
{
    int bid = blockIdx.x;
    int n0 = bid * 2, g = n0 >> 5;
    int l = threadIdx.x, lj = l & 15, lh = l >> 4;
    float di[2][2][3];
    #pragma unroll
    for (int h = 0; h < 2; ++h)
        #pragma unroll
        for (int dd = 0; dd < 2; ++dd) {
            int dstn = g*32 + dd*16 + lj;
            #pragma unroll
            for (int comp = 0; comp < 3; ++comp) {
                float d = frac[dstn*3 + comp] - frac[(n0+h)*3 + comp];
                d -= floorf(d);
                di[h][dd][comp] = d;
            }
        }
    #pragma unroll
    for (int kt = 0; kt < 2; ++kt)
        #pragma unroll
        for (int mt = 0; mt < 4; ++mt) {
            int h = mt >> 1, dd = mt & 1;
            unsigned int w[4];
            #pragma unroll
            for (int p = 0; p < 4; ++p) {
                float vv[2];
                #pragma unroll
                for (int e = 0; e < 2; ++e) {
                    int k = kt*32 + lh*8 + p*2 + e;
                    float val = 0.f;
                    if (k < 60) {
                        int isCos = k >= 30;
                        int dq = k - (isCos ? 30 : 0);
                        int comp = dq >= 20 ? 2 : (dq >= 10 ? 1 : 0);
                        int f = dq - comp*10;
                        float u = di[h][dd][comp] * (float)f;
                        u -= floorf(u);
                        val = isCos ? __builtin_amdgcn_cosf(u) : __builtin_amdgcn_sinf(u);
                    }
                    vv[e] = val;
                }
                w[p] = cvt_pk_bf16(vv[0], vv[1]);
            }
            uint4 pk = { w[0], w[1], w[2], w[3] };
            *(uint4*)&fdP[(((size_t)bid*8 + kt*4 + mt)*64 + l)*8] = pk;
        }
}

// nf0 = concat(emb,t)@Wl + bl : 16 rows x 256 cols per block, 256 blocks
__global__ __launch_bounds__(256) void k_init(
    const float* __restrict__ tvec, const float* __restrict__ emb,
    const unsigned short* __restrict__ WT, const float* __restrict__ bl,
    const int* __restrict__ atom_types, float* __restrict__ nf)
{
    __shared__ __align__(16) unsigned short cat_s[16*768];
    int n0 = (blockIdx.x >> 1) * 16, half = blockIdx.x & 1, tid = threadIdx.x;
    for (int idx = tid; idx < 16*192; idx += 256) {
        int m = idx / 192, q = idx - m * 192;
        int k4 = q * 4, n = n0 + m;
        float4 v;
        if (k4 < 512) v = *(const float4*)&emb[(size_t)(atom_types[n]-1)*512 + k4];
        else          v = *(const float4*)&tvec[(size_t)(n>>5)*256 + (k4-512)];
        uint2 pk = { cvt_pk_bf16(v.x, v.y), cvt_pk_bf16(v.z, v.w) };
        *(uint2*)&cat_s[m*768 + (k4 ^ ((m&7)<<3))] = pk;
    }
    __syncthreads();
    int w = tid >> 6, l = tid & 63, lj = l & 15, lh = l >> 4;
    f32x4 acc[4];
    #pragma unroll
    for (int nt = 0; nt < 4; ++nt) acc[nt] = (f32x4){0.f,0.f,0.f,0.f};
    for (int kt = 0; kt < 24; ++kt) {
        int k = kt*32 + lh*8;
        bf16x8 a = *(const bf16x8*)&cat_s[lj*768 + (k ^ ((lj&7)<<3))];
        #pragma unroll
        for (int nt = 0; nt < 4; ++nt) {
            bf16x8 b = *(const bf16x8*)&WT[(((size_t)kt*32 + half*16 + w*4 + nt)*64 + l)*8];
            acc[nt] = __builtin_amdgcn_mfma_f32_16x16x32_bf16(a, b, acc[nt], 0, 0, 0);
        }
    }
    #pragma unroll
    for (int nt = 0; nt < 4; ++nt) {
        int c = half*256 + w*64 + nt*16 + lj;
        float bv = bl[c];
        #pragma unroll
        for (int r = 0; r < 4; ++r)
            nf[(size_t)(n0 + lh*4 + r)*512 + c] = acc[nt][r] + bv;
    }
}

// 256 blocks: n-group (16 rows) x half. half0: U' = nf@W1a + latip@W1c + b1;
// half1: VTD f32 D-layout per graph. B-loads software-pipelined.
__global__ __launch_bounds__(256) void k_uv(
    const float* __restrict__ nf, const unsigned short* __restrict__ WT,
    const float* __restrict__ lat, const float* __restrict__ W1c,
    const float* __restrict__ b1, float* __restrict__ Up,
    float* __restrict__ VTD)
{
    __shared__ __align__(16) unsigned short a_s[16*512];
    int n0 = (blockIdx.x >> 1) * 16, half = blockIdx.x & 1;
    int g = n0 >> 5, tid = threadIdx.x;
    for (int idx = tid; idx < 16*128; idx += 256) {
        int m = idx >> 7, q = idx & 127;
        int k4 = q * 4;
        float4 v = *(const float4*)&nf[(size_t)(n0+m)*512 + k4];
        uint2 pk = { cvt_pk_bf16(v.x, v.y), cvt_pk_bf16(v.z, v.w) };
        *(uint2*)&a_s[m*512 + (k4 ^ ((m&7)<<3))] = pk;
    }
    __syncthreads();
    int w = tid >> 6, l = tid & 63, lj = l & 15, lh = l >> 4;
    const unsigned short* Wh = WT + (size_t)half*512*512;
    f32x4 acc[8];
    #pragma unroll
    for (int nt = 0; nt < 8; ++nt) acc[nt] = (f32x4){0.f,0.f,0.f,0.f};
    bf16x8 bcur[8], bnxt[8];
    #pragma unroll
    for (int nt = 0; nt < 8; ++nt)
        bcur[nt] = *(const bf16x8*)&Wh[(((size_t)0*32 + w*8 + nt)*64 + l)*8];
    for (int kt = 0; kt < 16; ++kt) {
        int k = kt*32 + lh*8;
        bf16x8 a = *(const bf16x8*)&a_s[lj*512 + (k ^ ((lj&7)<<3))];
        if (kt < 15) {
            #pragma unroll
            for (int nt = 0; nt < 8; ++nt)
                bnxt[nt] = *(const bf16x8*)&Wh[(((size_t)(kt+1)*32 + w*8 + nt)*64 + l)*8];
        }
        #pragma unroll
        for (int nt = 0; nt < 8; ++nt)
            acc[nt] = __builtin_amdgcn_mfma_f32_16x16x32_bf16(a, bcur[nt], acc[nt], 0, 0, 0);
        #pragma unroll
        for (int nt = 0; nt < 8; ++nt) bcur[nt] = bnxt[nt];
    }
    if (half == 0) {
        float L[9], lip[9];
        #pragma unroll
        for (int i = 0; i < 9; ++i) L[i] = lat[g*9 + i];
        #pragma unroll
        for (int i = 0; i < 3; ++i)
            #pragma unroll
            for (int kk = 0; kk < 3; ++kk)
                lip[i*3+kk] = L[i*3]*L[kk*3] + L[i*3+1]*L[kk*3+1] + L[i*3+2]*L[kk*3+2];
        #pragma unroll
        for (int nt = 0; nt < 8; ++nt) {
            int c = w*128 + nt*16 + lj;
            float p3 = b1[c];
            #pragma unroll
            for (int t9 = 0; t9 < 9; ++t9) p3 += lip[t9] * W1c[t9*512 + c];
            #pragma unroll
            for (int r = 0; r < 4; ++r)
                Up[(size_t)(n0 + lh*4 + r)*512 + c] = acc[nt][r] + p3;
        }
    } else {
        int dd = (n0 & 31) >> 4;
        #pragma unroll
        for (int nt = 0; nt < 8; ++nt) {
            int ct = w*8 + nt;
            #pragma unroll
            for (int rr = 0; rr < 4; ++rr)
                VTD[(size_t)g*16384 + ct*512 + dd*256 + (lh*4+rr)*16 + lj] = acc[nt][rr];
        }
    }
}

// fused edge pipeline: 2 src nodes/block (M=64), 512 threads (8 waves), grid 1024.
__global__ __launch_bounds__(512) void k_edge(
    const float* __restrict__ Up, const float* __restrict__ VTD,
    const unsigned short* __restrict__ fdP,
    const unsigned short* __restrict__ W1dT,
    const unsigned short* __restrict__ W2T, const float* __restrict__ b2,
    float* __restrict__ agg)
{
    __shared__ __align__(16) unsigned short ef1_s[64*512];
    int n0 = blockIdx.x * 2, g = n0 >> 5, tid = threadIdx.x;
    int wid = tid >> 6, l = tid & 63, lj = l & 15, lh = l >> 4;

    // ---------------- stage 1 ----------------
    {
        bf16x8 fdf[2][4];
        #pragma unroll
        for (int kt = 0; kt < 2; ++kt)
            #pragma unroll
            for (int mt = 0; mt < 4; ++mt)
                fdf[kt][mt] = *(const bf16x8*)&fdP[(((size_t)blockIdx.x*8 + kt*4 + mt)*64 + l)*8];

        #pragma unroll
        for (int q = 0; q < 4; ++q) {
            int ct = wid*4 + q;
            f32x4 a1[4];
            #pragma unroll
            for (int mt = 0; mt < 4; ++mt)
                a1[mt] = *(const f32x4*)&VTD[(size_t)g*16384 + ct*512 + (mt&1)*256 + lj*16 + lh*4];
            #pragma unroll
            for (int kt = 0; kt < 2; ++kt) {
                bf16x8 wf = *(const bf16x8*)&W1dT[(((size_t)kt*32 + ct)*64 + l)*8];
                #pragma unroll
                for (int mt = 0; mt < 4; ++mt)
                    a1[mt] = __builtin_amdgcn_mfma_f32_16x16x32_bf16(wf, fdf[kt][mt], a1[mt], 0, 0, 0);
            }
            int c0 = wid*64 + q*16 + lh*4;
            float4 bs0 = *(const float4*)&Up[(size_t)n0*512 + c0];
            float4 bs1 = *(const float4*)&Up[(size_t)(n0+1)*512 + c0];
            #pragma unroll
            for (int mt = 0; mt < 4; ++mt) {
                float4 bb = (mt >> 1) ? bs1 : bs0;
                int m = mt*16 + lj;
                float x0 = silu_f(a1[mt][0] + bb.x);
                float x1 = silu_f(a1[mt][1] + bb.y);
                float x2 = silu_f(a1[mt][2] + bb.z);
                float x3 = silu_f(a1[mt][3] + bb.w);
                uint2 pk = { cvt_pk_bf16(x0, x1), cvt_pk_bf16(x2, x3) };
                *(uint2*)&ef1_s[m*512 + (c0 ^ ((m&7)<<3))] = pk;
            }
        }
    }
    __syncthreads();

    // ---------------- stage 2 (barrier-free, B software-pipelined) ----------------
    f32x4 acc2[4][4];
    #pragma unroll
    for (int mt = 0; mt < 4; ++mt)
        #pragma unroll
        for (int nt = 0; nt < 4; ++nt) acc2[mt][nt] = (f32x4){0.f,0.f,0.f,0.f};

    bf16x8 bcur[4], bnxt[4];
    #pragma unroll
    for (int nt = 0; nt < 4; ++nt)
        bcur[nt] = *(const bf16x8*)&W2T[(((size_t)0*32 + wid*4 + nt)*64 + l)*8];

    for (int kt = 0; kt < 16; ++kt) {
        int k = kt*32 + lh*8;
        bf16x8 af[4];
        #pragma unroll
        for (int mt = 0; mt < 4; ++mt) {
            int m = mt*16 + lj;
            af[mt] = *(const bf16x8*)&ef1_s[m*512 + (k ^ ((m&7)<<3))];
        }
        if (kt < 15) {
            #pragma unroll
            for (int nt = 0; nt < 4; ++nt)
                bnxt[nt] = *(const bf16x8*)&W2T[(((size_t)(kt+1)*32 + wid*4 + nt)*64 + l)*8];
        }
        __builtin_amdgcn_s_setprio(1);
        #pragma unroll
        for (int nt = 0; nt < 4; ++nt) {
            #pragma unroll
            for (int mt = 0; mt < 4; ++mt)
                acc2[mt][nt] = __builtin_amdgcn_mfma_f32_16x16x32_bf16(af[mt], bcur[nt], acc2[mt][nt], 0, 0, 0);
        }
        __builtin_amdgcn_s_setprio(0);
        #pragma unroll
        for (int nt = 0; nt < 4; ++nt) bcur[nt] = bnxt[nt];
    }

    // epilogue: silu + per-node column mean
    #pragma unroll
    for (int nt = 0; nt < 4; ++nt) {
        int cc = wid*64 + nt*16 + lj;
        float bv = b2[cc];
        float s0 = 0.f, s1 = 0.f;
        #pragma unroll
        for (int mt = 0; mt < 4; ++mt)
            #pragma unroll
            for (int r = 0; r < 4; ++r) {
                float x = silu_f(acc2[mt][nt][r] + bv);
                if (mt < 2) s0 += x; else s1 += x;
            }
        s0 += __shfl_xor(s0, 16); s0 += __shfl_xor(s0, 32);
        s1 += __shfl_xor(s1, 16); s1 += __shfl_xor(s1, 32);
        if (lh == 0) {
            agg[(size_t)n0*512 + cc]     = s0 * (1.0f/32.0f);
            agg[(size_t)(n0+1)*512 + cc] = s1 * (1.0f/32.0f);
        }
    }
}

// h1 = silu([nf,agg]@nW1 + b1) -> bf16 global ; 16 rows x 256 cols, 256 blocks
__global__ __launch_bounds__(256) void k_node1(
    const float* __restrict__ nf, const float* __restrict__ agg,
    const unsigned short* __restrict__ W1T, const float* __restrict__ b1,
    unsigned short* __restrict__ h1g)
{
    __shared__ __align__(16) unsigned short nin_s[16*1024];
    int n0 = (blockIdx.x >> 1) * 16, half = blockIdx.x & 1, tid = threadIdx.x;
    for (int idx = tid; idx < 16*256; idx += 256) {
        int m = idx >> 8, q = idx & 255;
        int k4 = q * 4;
        float4 v = (k4 < 512) ? *(const float4*)&nf[(size_t)(n0+m)*512 + k4]
                              : *(const float4*)&agg[(size_t)(n0+m)*512 + (k4-512)];
        uint2 pk = { cvt_pk_bf16(v.x, v.y), cvt_pk_bf16(v.z, v.w) };
        *(uint2*)&nin_s[m*1024 + (k4 ^ ((m&7)<<3))] = pk;
    }
    __syncthreads();
    int w = tid >> 6, l = tid & 63, lj = l & 15, lh = l >> 4;
    f32x4 acc[4];
    #pragma unroll
    for (int nt = 0; nt < 4; ++nt) acc[nt] = (f32x4){0.f,0.f,0.f,0.f};
    bf16x8 bcur[4], bnxt[4];
    #pragma unroll
    for (int nt = 0; nt < 4; ++nt)
        bcur[nt] = *(const bf16x8*)&W1T[(((size_t)0*32 + half*16 + w*4 + nt)*64 + l)*8];
    for (int kt = 0; kt < 32; ++kt) {
        int k = kt*32 + lh*8;
        bf16x8 a = *(const bf16x8*)&nin_s[lj*1024 + (k ^ ((lj&7)<<3))];
        if (kt < 31) {
            #pragma unroll
            for (int nt = 0; nt < 4; ++nt)
                bnxt[nt] = *(const bf16x8*)&W1T[(((size_t)(kt+1)*32 + half*16 + w*4 + nt)*64 + l)*8];
        }
        #pragma unroll
        for (int nt = 0; nt < 4; ++nt)
            acc[nt] = __builtin_amdgcn_mfma_f32_16x16x32_bf16(a, bcur[nt], acc[nt], 0, 0, 0);
        #pragma unroll
        for (int nt = 0; nt < 4; ++nt) bcur[nt] = bnxt[nt];
    }
    #pragma unroll
    for (int nt = 0; nt < 4; ++nt) {
        int c = half*256 + w*64 + nt*16 + lj;
        float bv = b1[c];
        #pragma unroll
        for (int r = 0; r < 4; ++r)
            h1g[(size_t)(n0 + lh*4 + r)*512 + c] = f2bf(silu_f(acc[nt][r] + bv));
    }
}

// nf += silu(h1@nW2 + b2) ; 16 rows x 256 cols, 256 blocks
__global__ __launch_bounds__(256) void k_node2(
    float* __restrict__ nf, const unsigned short* __restrict__ h1g,
    const unsigned short* __restrict__ W2T, const float* __restrict__ b2)
{
    __shared__ __align__(16) unsigned short h1_s[16*512];
    int n0 = (blockIdx.x >> 1) * 16, half = blockIdx.x & 1, tid = threadIdx.x;
    for (int idx = tid; idx < 16*64; idx += 256) {
        int m = idx >> 6, k8 = (idx & 63) * 8;
        bf16x8 v = *(const bf16x8*)&h1g[(size_t)(n0+m)*512 + k8];
        *(bf16x8*)&h1_s[m*512 + (k8 ^ ((m&7)<<3))] = v;
    }
    __syncthreads();
    int w = tid >> 6, l = tid & 63, lj = l & 15, lh = l >> 4;
    f32x4 acc[4];
    #pragma unroll
    for (int nt = 0; nt < 4; ++nt) acc[nt] = (f32x4){0.f,0.f,0.f,0.f};
    bf16x8 bcur[4], bnxt[4];
    #pragma unroll
    for (int nt = 0; nt < 4; ++nt)
        bcur[nt] = *(const bf16x8*)&W2T[(((size_t)0*32 + half*16 + w*4 + nt)*64 + l)*8];
    for (int kt = 0; kt < 16; ++kt) {
        int k = kt*32 + lh*8;
        bf16x8 a = *(const bf16x8*)&h1_s[lj*512 + (k ^ ((lj&7)<<3))];
        if (kt < 15) {
            #pragma unroll
            for (int nt = 0; nt < 4; ++nt)
                bnxt[nt] = *(const bf16x8*)&W2T[(((size_t)(kt+1)*32 + half*16 + w*4 + nt)*64 + l)*8];
        }
        #pragma unroll
        for (int nt = 0; nt < 4; ++nt)
            acc[nt] = __builtin_amdgcn_mfma_f32_16x16x32_bf16(a, bcur[nt], acc[nt], 0, 0, 0);
        #pragma unroll
        for (int nt = 0; nt < 4; ++nt) bcur[nt] = bnxt[nt];
    }
    #pragma unroll
    for (int nt = 0; nt < 4; ++nt) {
        int c = half*256 + w*64 + nt*16 + lj;
        float bv = b2[c];
        #pragma unroll
        for (int r = 0; r < 4; ++r) {
            size_t o = (size_t)(n0 + lh*4 + r)*512 + c;
            nf[o] = nf[o] + silu_f(acc[nt][r] + bv);
        }
    }
}

// coord_out: 64 blocks x 256 thr
__global__ __launch_bounds__(256) void k_coord(const float* __restrict__ nf,
                                               const float* __restrict__ cW,
                                               float* __restrict__ out) {
    int b = blockIdx.x, t = threadIdx.x;
    int nl = t >> 3, s = t & 7;
    int n = b*32 + nl;
    const float* row = nf + (size_t)n*512 + s*64;
    float p0 = 0.f, p1 = 0.f, p2 = 0.f;
    #pragma unroll
    for (int k4 = 0; k4 < 64; k4 += 4) {
        float4 v = *(const float4*)&row[k4];
        int kg = s*64 + k4;
        p0 += v.x*cW[(kg+0)*3+0] + v.y*cW[(kg+1)*3+0] + v.z*cW[(kg+2)*3+0] + v.w*cW[(kg+3)*3+0];
        p1 += v.x*cW[(kg+0)*3+1] + v.y*cW[(kg+1)*3+1] + v.z*cW[(kg+2)*3+1] + v.w*cW[(kg+3)*3+1];
        p2 += v.x*cW[(kg+0)*3+2] + v.y*cW[(kg+1)*3+2] + v.z*cW[(kg+2)*3+2] + v.w*cW[(kg+3)*3+2];
    }
    p0 += __shfl_xor(p0, 1); p0 += __shfl_xor(p0, 2); p0 += __shfl_xor(p0, 4);
    p1 += __shfl_xor(p1, 1); p1 += __shfl_xor(p1, 2); p1 += __shfl_xor(p1, 4);
    p2 += __shfl_xor(p2, 1); p2 += __shfl_xor(p2, 2); p2 += __shfl_xor(p2, 4);
    if (s == 0) {
        out[576 + n*3 + 0] = p0;
        out[576 + n*3 + 1] = p1;
        out[576 + n*3 + 2] = p2;
    }
}

__global__ __launch_bounds__(256) void k_graph(const float* __restrict__ nf,
                                               const float* __restrict__ lW,
                                               const float* __restrict__ lat,
                                               float* __restrict__ out) {
    __shared__ float gf[512];
    __shared__ float lo9[9];
    int b = blockIdx.x, tid = threadIdx.x;
    float s0 = 0.f, s1 = 0.f;
    for (int r = 0; r < 32; ++r) {
        s0 += nf[(b * 32 + r) * 512 + tid];
        s1 += nf[(b * 32 + r) * 512 + tid + 256];
    }
    gf[tid]       = s0 * (1.f / 32.f);
    gf[tid + 256] = s1 * (1.f / 32.f);
    __syncthreads();
    if (tid < 9) {
        float s = 0.f;
        for (int k = 0; k < 512; ++k) s += gf[k] * lW[k * 9 + tid];
        lo9[tid] = s;
    }
    __syncthreads();
    if (tid < 9) {
        int i = tid / 3, kk = tid - (tid / 3) * 3;
        float s = lo9[i*3+0] * lat[b*9 + 0*3 + kk]
                + lo9[i*3+1] * lat[b*9 + 1*3 + kk]
                + lo9[i*3+2] * lat[b*9 + 2*3 + kk];
        out[b * 9 + tid] = s;
    }
}

extern "C" void kernel_launch(void* const* d_in, const int* in_sizes, int n_in,
                              void* d_out, int out_size, void* d_ws, size_t ws_size,
                              hipStream_t stream)
{
    const float* t    = (const float*)d_in[0];
    const float* frac = (const float*)d_in[1];
    const float* lat  = (const float*)d_in[2];
    const float* emb  = (const float*)d_in[3];
    const float* Wl   = (const float*)d_in[4];
    const float* bl   = (const float*)d_in[5];
    const float* eW1  = (const float*)d_in[6];
    const float* eb1  = (const float*)d_in[7];
    const float* eW2  = (const float*)d_in[8];
    const float* eb2  = (const float*)d_in[9];
    const float* nW1  = (const float*)d_in[10];
    const float* nb1  = (const float*)d_in[11];
    const float* nW2  = (const float*)d_in[12];
    const float* nb2  = (const float*)d_in[13];
    const float* cW   = (const float*)d_in[14];
    const float* lW   = (const float*)d_in[15];
    const int* atom_types = (const int*)d_in[16];

    float* out  = (float*)d_out;
    float* wsf  = (float*)d_ws;
    float* nf   = wsf + NF_OFF;
    float* Uagg = wsf + UAGG_OFF;   // U' during k_edge; agg after (row-exclusive)
    float* VTD  = wsf + VTD_OFF;
    unsigned short* h1g = (unsigned short*)(wsf + H1_OFF);
    unsigned short* wbf = (unsigned short*)(wsf + WBF_OFF);
    unsigned short* fdP = (unsigned short*)(wsf + FDP_OFF);

    k_prep<<<384 + 4*1568, 256, 0, stream>>>(Wl, eW1, eW2, nW1, nW2, wbf);
    k_fd<<<1024, 64, 0, stream>>>(frac, fdP);
    k_init<<<256, 256, 0, stream>>>(t, emb, wbf, bl, atom_types, nf);
    for (int l = 0; l < 4; ++l) {
        const unsigned short* base = wbf + SZ_INITT + (size_t)l * SZ_LAYER;
        const unsigned short* w1dT = base + SZ_UVT;
        const unsigned short* w2T  = w1dT + SZ_W1DT;
        const unsigned short* nw1T = w2T + SZ_W2T;
        const unsigned short* nw2T = nw1T + SZ_NW1T;
        k_uv<<<256, 256, 0, stream>>>(nf, base, lat,
                                      eW1 + (size_t)l*1093*512 + 1024*512,
                                      eb1 + l*512, Uagg, VTD);
        k_edge<<<1024, 512, 0, stream>>>(Uagg, VTD, fdP, w1dT, w2T,
                                         eb2 + l*512, Uagg);
        k_node1<<<256, 256, 0, stream>>>(nf, Uagg, nw1T, nb1 + l*512, h1g);
        k_node2<<<256, 256, 0, stream>>>(nf, h1g, nw2T, nb2 + l*512);
    }
    k_coord<<<64, 256, 0, stream>>>(nf, cW, out);
    k_graph<<<64, 256, 0, stream>>>(nf, lW, lat, out);
}

// Round 13
// 355.356 us; speedup vs baseline: 1.7572x; 1.0603x over previous
//
#include <hip/hip_runtime.h>
#include <math.h>

// B=64 graphs, A=32 atoms, N=2048 nodes, E=65536 edges, H=512, LAT=256, L=4, DIS=60, EIN=1093
// Weights pre-packed in MFMA B-fragment order: tile (kt,nt) of W^T[512][K] at
// ((kt*32+nt)*64+lane)*8 ; lane (lj=l&15, lh=l>>4) holds W^T[nt*16+lj][kt*32+lh*8..+8].
// Activations (nf, h1, agg) ALSO kept in A-fragment-packed bf16 global buffers:
//   element (row m in 16-group ng, col c) at ((ng*16 + c/32)*64 + m + 16*((c>>3)&3))*8 + (c&7)
// so node-side GEMMs need NO LDS staging at all (r12 PMC: staging was the node-side cost).
// fd sinusoid fragments precomputed once (layer-invariant). V emitted in f32 D-layout.

typedef short bf16x8 __attribute__((ext_vector_type(8)));
typedef float f32x4 __attribute__((ext_vector_type(4)));

__device__ __forceinline__ float silu_f(float x) {
    float e = __builtin_amdgcn_exp2f(x * -1.44269504088896f);
    return x * __builtin_amdgcn_rcpf(1.0f + e);
}
__device__ __forceinline__ unsigned short f2bf(float x) {
    unsigned int u = __float_as_uint(x);
    u += 0x7fffu + ((u >> 16) & 1u);
    return (unsigned short)(u >> 16);
}
__device__ __forceinline__ unsigned int cvt_pk_bf16(float lo, float hi) {
    unsigned int r;
    asm("v_cvt_pk_bf16_f32 %0, %1, %2" : "=v"(r) : "v"(lo), "v"(hi));
    return r;
}
// A-fragment-packed index for element (row m of group ng, col c)
__device__ __forceinline__ size_t apack_idx(int ng, int m, int c) {
    return ((size_t)(ng*16 + (c >> 5))*64 + (m + 16*((c >> 3) & 3)))*8 + (c & 7);
}

// ---- workspace layout (float offsets) ----
#define NF_OFF    0                              // f32 2048*512
#define UP_OFF    (2048*512)                     // f32 2048*512 (U')
#define VTD_OFF   (2*2048*512)                   // f32 64*16384 = 1048576
#define NFP_OFF   (VTD_OFF + 1048576)            // u16 2048*512 -> 524288 floats
#define H1P_OFF   (NFP_OFF + 524288)             // u16 2048*512
#define AGGP_OFF  (H1P_OFF + 524288)             // u16 2048*512
#define WBF_OFF   (AGGP_OFF + 524288)
// bf16 weight region sizes (ushort elements)
#define SZ_INITT (512*768)
#define SZ_UVT   (1024*512)
#define SZ_W1DT  (512*64)
#define SZ_W2T   (512*512)
#define SZ_NW1T  (512*1024)
#define SZ_NW2T  (512*512)
#define SZ_LAYER (SZ_UVT+SZ_W1DT+SZ_W2T+SZ_NW1T+SZ_NW2T)
#define WBF_FLOATS ((SZ_INITT + 4*SZ_LAYER + 1)/2)
#define FDP_OFF   (WBF_OFF + WBF_FLOATS)         // u16 1024*8*512

// ---- weight transpose+convert+fragment-pack: f32 [K][512] -> packed bf16 ----
__global__ __launch_bounds__(256) void k_prep(
    const float* __restrict__ Wl, const float* __restrict__ eW1,
    const float* __restrict__ eW2, const float* __restrict__ nW1,
    const float* __restrict__ nW2, unsigned short* __restrict__ wbf)
{
    __shared__ float tile[32][33];
    int bid = blockIdx.x;
    const float* src; int K; unsigned short* dst; int t;
    if (bid < 384) { src = Wl; K = 768; dst = wbf; t = bid; }
    else {
        int b = bid - 384; int l = b / 1568; int j = b - l * 1568;
        const float* e1 = eW1 + (size_t)l * 1093 * 512;
        unsigned short* base = wbf + SZ_INITT + (size_t)l * SZ_LAYER;
        if (j < 256)      { src = e1;                       K = 512;  dst = base;                                   t = j; }
        else if (j < 512) { src = e1 + 512*512;             K = 512;  dst = base + 512*512;                         t = j-256; }
        else if (j < 544) { src = e1 + 1033*512;            K = 60;   dst = base + SZ_UVT;                          t = j-512; }
        else if (j < 800) { src = eW2 + (size_t)l*512*512;  K = 512;  dst = base + SZ_UVT+SZ_W1DT;                  t = j-544; }
        else if (j <1312) { src = nW1 + (size_t)l*1024*512; K = 1024; dst = base + SZ_UVT+SZ_W1DT+SZ_W2T;           t = j-800; }
        else              { src = nW2 + (size_t)l*512*512;  K = 512;  dst = base + SZ_UVT+SZ_W1DT+SZ_W2T+SZ_NW1T;   t = j-1312; }
    }
    int tr = t >> 4, tc = t & 15;
    int k0 = tr * 32, nn0 = tc * 32;
    {
        int r8 = threadIdx.x >> 5, cc = threadIdx.x & 31;
        #pragma unroll
        for (int rr = 0; rr < 4; ++rr) {
            int row = rr*8 + r8;
            int k = k0 + row;
            tile[row][cc] = (k < K) ? src[(size_t)k*512 + nn0 + cc] : 0.f;
        }
    }
    __syncthreads();
    int nt_loc = threadIdx.x >> 7;
    int l = (threadIdx.x >> 1) & 63;
    int jh = threadIdx.x & 1;
    int lj = l & 15, lh = l >> 4;
    float v0 = tile[lh*8 + jh*4 + 0][nt_loc*16 + lj];
    float v1 = tile[lh*8 + jh*4 + 1][nt_loc*16 + lj];
    float v2 = tile[lh*8 + jh*4 + 2][nt_loc*16 + lj];
    float v3 = tile[lh*8 + jh*4 + 3][nt_loc*16 + lj];
    uint2 pk = { cvt_pk_bf16(v0, v1), cvt_pk_bf16(v2, v3) };
    *(uint2*)&dst[((size_t)(tr*32 + tc*2 + nt_loc)*64 + l)*8 + jh*4] = pk;
}

// fd sinusoid B-fragments, once for all layers: fdP[block][kt*4+mt][lane][8]
__global__ __launch_bounds__(64) void k_fd(const float* __restrict__ frac,
                                           unsigned short* __restrict__ fdP)
{
    int bid = blockIdx.x;
    int n0 = bid * 2, g = n0 >> 5;
    int l = threadIdx.x, lj = l & 15, lh = l >> 4;
    float di[2][2][3];
    #pragma unroll
    for (int h = 0; h < 2; ++h)
        #pragma unroll
        for (int dd = 0; dd < 2; ++dd) {
            int dstn = g*32 + dd*16 + lj;
            #pragma unroll
            for (int comp = 0; comp < 3; ++comp) {
                float d = frac[dstn*3 + comp] - frac[(n0+h)*3 + comp];
                d -= floorf(d);
                di[h][dd][comp] = d;
            }
        }
    #pragma unroll
    for (int kt = 0; kt < 2; ++kt)
        #pragma unroll
        for (int mt = 0; mt < 4; ++mt) {
            int h = mt >> 1, dd = mt & 1;
            unsigned int w[4];
            #pragma unroll
            for (int p = 0; p < 4; ++p) {
                float vv[2];
                #pragma unroll
                for (int e = 0; e < 2; ++e) {
                    int k = kt*32 + lh*8 + p*2 + e;
                    float val = 0.f;
                    if (k < 60) {
                        int isCos = k >= 30;
                        int dq = k - (isCos ? 30 : 0);
                        int comp = dq >= 20 ? 2 : (dq >= 10 ? 1 : 0);
                        int f = dq - comp*10;
                        float u = di[h][dd][comp] * (float)f;
                        u -= floorf(u);
                        val = isCos ? __builtin_amdgcn_cosf(u) : __builtin_amdgcn_sinf(u);
                    }
                    vv[e] = val;
                }
                w[p] = cvt_pk_bf16(vv[0], vv[1]);
            }
            uint4 pk = { w[0], w[1], w[2], w[3] };
            *(uint4*)&fdP[(((size_t)bid*8 + kt*4 + mt)*64 + l)*8] = pk;
        }
}

// nf0 = concat(emb,t)@Wl + bl : 16 rows x 256 cols per block, 256 blocks.
// Writes nf (f32) AND nfP (A-packed bf16).
__global__ __launch_bounds__(256) void k_init(
    const float* __restrict__ tvec, const float* __restrict__ emb,
    const unsigned short* __restrict__ WT, const float* __restrict__ bl,
    const int* __restrict__ atom_types, float* __restrict__ nf,
    unsigned short* __restrict__ nfP)
{
    __shared__ __align__(16) unsigned short cat_s[16*768];
    int ng = blockIdx.x >> 1, half = blockIdx.x & 1;
    int n0 = ng * 16, tid = threadIdx.x;
    for (int idx = tid; idx < 16*192; idx += 256) {
        int m = idx / 192, q = idx - m * 192;
        int k4 = q * 4, n = n0 + m;
        float4 v;
        if (k4 < 512) v = *(const float4*)&emb[(size_t)(atom_types[n]-1)*512 + k4];
        else          v = *(const float4*)&tvec[(size_t)(n>>5)*256 + (k4-512)];
        uint2 pk = { cvt_pk_bf16(v.x, v.y), cvt_pk_bf16(v.z, v.w) };
        *(uint2*)&cat_s[m*768 + (k4 ^ ((m&7)<<3))] = pk;
    }
    __syncthreads();
    int w = tid >> 6, l = tid & 63, lj = l & 15, lh = l >> 4;
    f32x4 acc[4];
    #pragma unroll
    for (int nt = 0; nt < 4; ++nt) acc[nt] = (f32x4){0.f,0.f,0.f,0.f};
    for (int kt = 0; kt < 24; ++kt) {
        int k = kt*32 + lh*8;
        bf16x8 a = *(const bf16x8*)&cat_s[lj*768 + (k ^ ((lj&7)<<3))];
        #pragma unroll
        for (int nt = 0; nt < 4; ++nt) {
            bf16x8 b = *(const bf16x8*)&WT[(((size_t)kt*32 + half*16 + w*4 + nt)*64 + l)*8];
            acc[nt] = __builtin_amdgcn_mfma_f32_16x16x32_bf16(a, b, acc[nt], 0, 0, 0);
        }
    }
    #pragma unroll
    for (int nt = 0; nt < 4; ++nt) {
        int c = half*256 + w*64 + nt*16 + lj;
        float bv = bl[c];
        #pragma unroll
        for (int r = 0; r < 4; ++r) {
            int m = lh*4 + r;
            float v = acc[nt][r] + bv;
            nf[(size_t)(n0 + m)*512 + c] = v;
            nfP[apack_idx(ng, m, c)] = f2bf(v);
        }
    }
}

// LDS-free uv: 512 blocks (ng, half, ch). A-frags direct from nfP.
// half0: U' = nf@W1a + latip@W1c + b1; half1: VTD f32 D-layout per graph
__global__ __launch_bounds__(256) void k_uv(
    const unsigned short* __restrict__ nfP, const unsigned short* __restrict__ WT,
    const float* __restrict__ lat, const float* __restrict__ W1c,
    const float* __restrict__ b1, float* __restrict__ Up,
    float* __restrict__ VTD)
{
    int ng = blockIdx.x >> 2, half = (blockIdx.x >> 1) & 1, ch = blockIdx.x & 1;
    int n0 = ng * 16, g = n0 >> 5, tid = threadIdx.x;
    int w = tid >> 6, l = tid & 63, lj = l & 15, lh = l >> 4;
    const unsigned short* Wh = WT + (size_t)half*512*512;
    f32x4 acc[4];
    #pragma unroll
    for (int nt = 0; nt < 4; ++nt) acc[nt] = (f32x4){0.f,0.f,0.f,0.f};
    bf16x8 acur, anxt, bcur[4], bnxt[4];
    acur = *(const bf16x8*)&nfP[((size_t)(ng*16 + 0)*64 + l)*8];
    #pragma unroll
    for (int nt = 0; nt < 4; ++nt)
        bcur[nt] = *(const bf16x8*)&Wh[(((size_t)0*32 + ch*16 + w*4 + nt)*64 + l)*8];
    for (int kt = 0; kt < 16; ++kt) {
        if (kt < 15) {
            anxt = *(const bf16x8*)&nfP[((size_t)(ng*16 + kt + 1)*64 + l)*8];
            #pragma unroll
            for (int nt = 0; nt < 4; ++nt)
                bnxt[nt] = *(const bf16x8*)&Wh[(((size_t)(kt+1)*32 + ch*16 + w*4 + nt)*64 + l)*8];
        }
        #pragma unroll
        for (int nt = 0; nt < 4; ++nt)
            acc[nt] = __builtin_amdgcn_mfma_f32_16x16x32_bf16(acur, bcur[nt], acc[nt], 0, 0, 0);
        acur = anxt;
        #pragma unroll
        for (int nt = 0; nt < 4; ++nt) bcur[nt] = bnxt[nt];
    }
    if (half == 0) {
        float L[9], lip[9];
        #pragma unroll
        for (int i = 0; i < 9; ++i) L[i] = lat[g*9 + i];
        #pragma unroll
        for (int i = 0; i < 3; ++i)
            #pragma unroll
            for (int kk = 0; kk < 3; ++kk)
                lip[i*3+kk] = L[i*3]*L[kk*3] + L[i*3+1]*L[kk*3+1] + L[i*3+2]*L[kk*3+2];
        #pragma unroll
        for (int nt = 0; nt < 4; ++nt) {
            int c = ch*256 + w*64 + nt*16 + lj;
            float p3 = b1[c];
            #pragma unroll
            for (int t9 = 0; t9 < 9; ++t9) p3 += lip[t9] * W1c[t9*512 + c];
            #pragma unroll
            for (int r = 0; r < 4; ++r)
                Up[(size_t)(n0 + lh*4 + r)*512 + c] = acc[nt][r] + p3;
        }
    } else {
        int dd = (n0 & 31) >> 4;
        #pragma unroll
        for (int nt = 0; nt < 4; ++nt) {
            int ct = ch*16 + w*4 + nt;
            #pragma unroll
            for (int rr = 0; rr < 4; ++rr)
                VTD[(size_t)g*16384 + ct*512 + dd*256 + (lh*4+rr)*16 + lj] = acc[nt][rr];
        }
    }
}

// fused edge pipeline: 2 src nodes/block (M=64), 512 threads (8 waves), grid 1024.
// Epilogue writes aggP (A-packed bf16) directly.
__global__ __launch_bounds__(512) void k_edge(
    const float* __restrict__ Up, const float* __restrict__ VTD,
    const unsigned short* __restrict__ fdP,
    const unsigned short* __restrict__ W1dT,
    const unsigned short* __restrict__ W2T, const float* __restrict__ b2,
    unsigned short* __restrict__ aggP)
{
    __shared__ __align__(16) unsigned short ef1_s[64*512];
    int n0 = blockIdx.x * 2, g = n0 >> 5, tid = threadIdx.x;
    int wid = tid >> 6, l = tid & 63, lj = l & 15, lh = l >> 4;

    // ---------------- stage 1 ----------------
    {
        bf16x8 fdf[2][4];
        #pragma unroll
        for (int kt = 0; kt < 2; ++kt)
            #pragma unroll
            for (int mt = 0; mt < 4; ++mt)
                fdf[kt][mt] = *(const bf16x8*)&fdP[(((size_t)blockIdx.x*8 + kt*4 + mt)*64 + l)*8];

        #pragma unroll
        for (int q = 0; q < 4; ++q) {
            int ct = wid*4 + q;
            f32x4 a1[4];
            #pragma unroll
            for (int mt = 0; mt < 4; ++mt)
                a1[mt] = *(const f32x4*)&VTD[(size_t)g*16384 + ct*512 + (mt&1)*256 + lj*16 + lh*4];
            #pragma unroll
            for (int kt = 0; kt < 2; ++kt) {
                bf16x8 wf = *(const bf16x8*)&W1dT[(((size_t)kt*32 + ct)*64 + l)*8];
                #pragma unroll
                for (int mt = 0; mt < 4; ++mt)
                    a1[mt] = __builtin_amdgcn_mfma_f32_16x16x32_bf16(wf, fdf[kt][mt], a1[mt], 0, 0, 0);
            }
            int c0 = wid*64 + q*16 + lh*4;
            float4 bs0 = *(const float4*)&Up[(size_t)n0*512 + c0];
            float4 bs1 = *(const float4*)&Up[(size_t)(n0+1)*512 + c0];
            #pragma unroll
            for (int mt = 0; mt < 4; ++mt) {
                float4 bb = (mt >> 1) ? bs1 : bs0;
                int m = mt*16 + lj;
                float x0 = silu_f(a1[mt][0] + bb.x);
                float x1 = silu_f(a1[mt][1] + bb.y);
                float x2 = silu_f(a1[mt][2] + bb.z);
                float x3 = silu_f(a1[mt][3] + bb.w);
                uint2 pk = { cvt_pk_bf16(x0, x1), cvt_pk_bf16(x2, x3) };
                *(uint2*)&ef1_s[m*512 + (c0 ^ ((m&7)<<3))] = pk;
            }
        }
    }
    __syncthreads();

    // ---------------- stage 2 (barrier-free, B software-pipelined) ----------------
    f32x4 acc2[4][4];
    #pragma unroll
    for (int mt = 0; mt < 4; ++mt)
        #pragma unroll
        for (int nt = 0; nt < 4; ++nt) acc2[mt][nt] = (f32x4){0.f,0.f,0.f,0.f};

    bf16x8 bcur[4], bnxt[4];
    #pragma unroll
    for (int nt = 0; nt < 4; ++nt)
        bcur[nt] = *(const bf16x8*)&W2T[(((size_t)0*32 + wid*4 + nt)*64 + l)*8];

    for (int kt = 0; kt < 16; ++kt) {
        int k = kt*32 + lh*8;
        bf16x8 af[4];
        #pragma unroll
        for (int mt = 0; mt < 4; ++mt) {
            int m = mt*16 + lj;
            af[mt] = *(const bf16x8*)&ef1_s[m*512 + (k ^ ((m&7)<<3))];
        }
        if (kt < 15) {
            #pragma unroll
            for (int nt = 0; nt < 4; ++nt)
                bnxt[nt] = *(const bf16x8*)&W2T[(((size_t)(kt+1)*32 + wid*4 + nt)*64 + l)*8];
        }
        __builtin_amdgcn_s_setprio(1);
        #pragma unroll
        for (int nt = 0; nt < 4; ++nt) {
            #pragma unroll
            for (int mt = 0; mt < 4; ++mt)
                acc2[mt][nt] = __builtin_amdgcn_mfma_f32_16x16x32_bf16(af[mt], bcur[nt], acc2[mt][nt], 0, 0, 0);
        }
        __builtin_amdgcn_s_setprio(0);
        #pragma unroll
        for (int nt = 0; nt < 4; ++nt) bcur[nt] = bnxt[nt];
    }

    // epilogue: silu + per-node column mean -> aggP (A-packed bf16)
    int ngg = n0 >> 4, m0 = n0 & 15;
    #pragma unroll
    for (int nt = 0; nt < 4; ++nt) {
        int cc = wid*64 + nt*16 + lj;
        float bv = b2[cc];
        float s0 = 0.f, s1 = 0.f;
        #pragma unroll
        for (int mt = 0; mt < 4; ++mt)
            #pragma unroll
            for (int r = 0; r < 4; ++r) {
                float x = silu_f(acc2[mt][nt][r] + bv);
                if (mt < 2) s0 += x; else s1 += x;
            }
        s0 += __shfl_xor(s0, 16); s0 += __shfl_xor(s0, 32);
        s1 += __shfl_xor(s1, 16); s1 += __shfl_xor(s1, 32);
        if (lh == 0) {
            aggP[apack_idx(ngg, m0,     cc)] = f2bf(s0 * (1.0f/32.0f));
            aggP[apack_idx(ngg, m0 + 1, cc)] = f2bf(s1 * (1.0f/32.0f));
        }
    }
}

// LDS-free node GEMM1: 512 blocks (ng, cq). h1P = silu([nfP,aggP]@nW1 + b1), A-packed.
__global__ __launch_bounds__(256) void k_node1(
    const unsigned short* __restrict__ nfP, const unsigned short* __restrict__ aggP,
    const unsigned short* __restrict__ W1T, const float* __restrict__ b1,
    unsigned short* __restrict__ h1P)
{
    int ng = blockIdx.x >> 2, cq = blockIdx.x & 3, tid = threadIdx.x;
    int w = tid >> 6, l = tid & 63, lj = l & 15, lh = l >> 4;
    f32x4 acc[2];
    acc[0] = (f32x4){0.f,0.f,0.f,0.f};
    acc[1] = (f32x4){0.f,0.f,0.f,0.f};
    bf16x8 acur, anxt, bcur[2], bnxt[2];
    acur = *(const bf16x8*)&nfP[((size_t)(ng*16 + 0)*64 + l)*8];
    #pragma unroll
    for (int nt = 0; nt < 2; ++nt)
        bcur[nt] = *(const bf16x8*)&W1T[(((size_t)0*32 + cq*8 + w*2 + nt)*64 + l)*8];
    for (int kt = 0; kt < 32; ++kt) {
        if (kt < 31) {
            int kn = kt + 1;
            anxt = (kn < 16)
                ? *(const bf16x8*)&nfP[((size_t)(ng*16 + kn)*64 + l)*8]
                : *(const bf16x8*)&aggP[((size_t)(ng*16 + kn - 16)*64 + l)*8];
            #pragma unroll
            for (int nt = 0; nt < 2; ++nt)
                bnxt[nt] = *(const bf16x8*)&W1T[(((size_t)kn*32 + cq*8 + w*2 + nt)*64 + l)*8];
        }
        #pragma unroll
        for (int nt = 0; nt < 2; ++nt)
            acc[nt] = __builtin_amdgcn_mfma_f32_16x16x32_bf16(acur, bcur[nt], acc[nt], 0, 0, 0);
        acur = anxt;
        #pragma unroll
        for (int nt = 0; nt < 2; ++nt) bcur[nt] = bnxt[nt];
    }
    #pragma unroll
    for (int nt = 0; nt < 2; ++nt) {
        int c = cq*128 + w*32 + nt*16 + lj;
        float bv = b1[c];
        #pragma unroll
        for (int r = 0; r < 4; ++r) {
            int m = lh*4 + r;
            h1P[apack_idx(ng, m, c)] = f2bf(silu_f(acc[nt][r] + bv));
        }
    }
}

// LDS-free node GEMM2: 512 blocks (ng, cq). nf += silu(h1P@nW2 + b2); writes nfP.
__global__ __launch_bounds__(256) void k_node2(
    float* __restrict__ nf, const unsigned short* __restrict__ h1P,
    const unsigned short* __restrict__ W2T, const float* __restrict__ b2,
    unsigned short* __restrict__ nfP)
{
    int ng = blockIdx.x >> 2, cq = blockIdx.x & 3, tid = threadIdx.x;
    int n0 = ng * 16;
    int w = tid >> 6, l = tid & 63, lj = l & 15, lh = l >> 4;
    f32x4 acc[2];
    acc[0] = (f32x4){0.f,0.f,0.f,0.f};
    acc[1] = (f32x4){0.f,0.f,0.f,0.f};
    bf16x8 acur, anxt, bcur[2], bnxt[2];
    acur = *(const bf16x8*)&h1P[((size_t)(ng*16 + 0)*64 + l)*8];
    #pragma unroll
    for (int nt = 0; nt < 2; ++nt)
        bcur[nt] = *(const bf16x8*)&W2T[(((size_t)0*32 + cq*8 + w*2 + nt)*64 + l)*8];
    for (int kt = 0; kt < 16; ++kt) {
        if (kt < 15) {
            anxt = *(const bf16x8*)&h1P[((size_t)(ng*16 + kt + 1)*64 + l)*8];
            #pragma unroll
            for (int nt = 0; nt < 2; ++nt)
                bnxt[nt] = *(const bf16x8*)&W2T[(((size_t)(kt+1)*32 + cq*8 + w*2 + nt)*64 + l)*8];
        }
        #pragma unroll
        for (int nt = 0; nt < 2; ++nt)
            acc[nt] = __builtin_amdgcn_mfma_f32_16x16x32_bf16(acur, bcur[nt], acc[nt], 0, 0, 0);
        acur = anxt;
        #pragma unroll
        for (int nt = 0; nt < 2; ++nt) bcur[nt] = bnxt[nt];
    }
    #pragma unroll
    for (int nt = 0; nt < 2; ++nt) {
        int c = cq*128 + w*32 + nt*16 + lj;
        float bv = b2[c];
        #pragma unroll
        for (int r = 0; r < 4; ++r) {
            int m = lh*4 + r;
            size_t o = (size_t)(n0 + m)*512 + c;
            float v = nf[o] + silu_f(acc[nt][r] + bv);
            nf[o] = v;
            nfP[apack_idx(ng, m, c)] = f2bf(v);
        }
    }
}

// coord_out: 64 blocks x 256 thr
__global__ __launch_bounds__(256) void k_coord(const float* __restrict__ nf,
                                               const float* __restrict__ cW,
                                               float* __restrict__ out) {
    int b = blockIdx.x, t = threadIdx.x;
    int nl = t >> 3, s = t & 7;
    int n = b*32 + nl;
    const float* row = nf + (size_t)n*512 + s*64;
    float p0 = 0.f, p1 = 0.f, p2 = 0.f;
    #pragma unroll
    for (int k4 = 0; k4 < 64; k4 += 4) {
        float4 v = *(const float4*)&row[k4];
        int kg = s*64 + k4;
        p0 += v.x*cW[(kg+0)*3+0] + v.y*cW[(kg+1)*3+0] + v.z*cW[(kg+2)*3+0] + v.w*cW[(kg+3)*3+0];
        p1 += v.x*cW[(kg+0)*3+1] + v.y*cW[(kg+1)*3+1] + v.z*cW[(kg+2)*3+1] + v.w*cW[(kg+3)*3+1];
        p2 += v.x*cW[(kg+0)*3+2] + v.y*cW[(kg+1)*3+2] + v.z*cW[(kg+2)*3+2] + v.w*cW[(kg+3)*3+2];
    }
    p0 += __shfl_xor(p0, 1); p0 += __shfl_xor(p0, 2); p0 += __shfl_xor(p0, 4);
    p1 += __shfl_xor(p1, 1); p1 += __shfl_xor(p1, 2); p1 += __shfl_xor(p1, 4);
    p2 += __shfl_xor(p2, 1); p2 += __shfl_xor(p2, 2); p2 += __shfl_xor(p2, 4);
    if (s == 0) {
        out[576 + n*3 + 0] = p0;
        out[576 + n*3 + 1] = p1;
        out[576 + n*3 + 2] = p2;
    }
}

__global__ __launch_bounds__(256) void k_graph(const float* __restrict__ nf,
                                               const float* __restrict__ lW,
                                               const float* __restrict__ lat,
                                               float* __restrict__ out) {
    __shared__ float gf[512];
    __shared__ float lo9[9];
    int b = blockIdx.x, tid = threadIdx.x;
    float s0 = 0.f, s1 = 0.f;
    for (int r = 0; r < 32; ++r) {
        s0 += nf[(b * 32 + r) * 512 + tid];
        s1 += nf[(b * 32 + r) * 512 + tid + 256];
    }
    gf[tid]       = s0 * (1.f / 32.f);
    gf[tid + 256] = s1 * (1.f / 32.f);
    __syncthreads();
    if (tid < 9) {
        float s = 0.f;
        for (int k = 0; k < 512; ++k) s += gf[k] * lW[k * 9 + tid];
        lo9[tid] = s;
    }
    __syncthreads();
    if (tid < 9) {
        int i = tid / 3, kk = tid - (tid / 3) * 3;
        float s = lo9[i*3+0] * lat[b*9 + 0*3 + kk]
                + lo9[i*3+1] * lat[b*9 + 1*3 + kk]
                + lo9[i*3+2] * lat[b*9 + 2*3 + kk];
        out[b * 9 + tid] = s;
    }
}

extern "C" void kernel_launch(void* const* d_in, const int* in_sizes, int n_in,
                              void* d_out, int out_size, void* d_ws, size_t ws_size,
                              hipStream_t stream)
{
    const float* t    = (const float*)d_in[0];
    const float* frac = (const float*)d_in[1];
    const float* lat  = (const float*)d_in[2];
    const float* emb  = (const float*)d_in[3];
    const float* Wl   = (const float*)d_in[4];
    const float* bl   = (const float*)d_in[5];
    const float* eW1  = (const float*)d_in[6];
    const float* eb1  = (const float*)d_in[7];
    const float* eW2  = (const float*)d_in[8];
    const float* eb2  = (const float*)d_in[9];
    const float* nW1  = (const float*)d_in[10];
    const float* nb1  = (const float*)d_in[11];
    const float* nW2  = (const float*)d_in[12];
    const float* nb2  = (const float*)d_in[13];
    const float* cW   = (const float*)d_in[14];
    const float* lW   = (const float*)d_in[15];
    const int* atom_types = (const int*)d_in[16];

    float* out  = (float*)d_out;
    float* wsf  = (float*)d_ws;
    float* nf   = wsf + NF_OFF;
    float* Up   = wsf + UP_OFF;
    float* VTD  = wsf + VTD_OFF;
    unsigned short* nfP  = (unsigned short*)(wsf + NFP_OFF);
    unsigned short* h1P  = (unsigned short*)(wsf + H1P_OFF);
    unsigned short* aggP = (unsigned short*)(wsf + AGGP_OFF);
    unsigned short* wbf  = (unsigned short*)(wsf + WBF_OFF);
    unsigned short* fdP  = (unsigned short*)(wsf + FDP_OFF);

    k_prep<<<384 + 4*1568, 256, 0, stream>>>(Wl, eW1, eW2, nW1, nW2, wbf);
    k_fd<<<1024, 64, 0, stream>>>(frac, fdP);
    k_init<<<256, 256, 0, stream>>>(t, emb, wbf, bl, atom_types, nf, nfP);
    for (int l = 0; l < 4; ++l) {
        const unsigned short* base = wbf + SZ_INITT + (size_t)l * SZ_LAYER;
        const unsigned short* w1dT = base + SZ_UVT;
        const unsigned short* w2T  = w1dT + SZ_W1DT;
        const unsigned short* nw1T = w2T + SZ_W2T;
        const unsigned short* nw2T = nw1T + SZ_NW1T;
        k_uv<<<512, 256, 0, stream>>>(nfP, base, lat,
                                      eW1 + (size_t)l*1093*512 + 1024*512,
                                      eb1 + l*512, Up, VTD);
        k_edge<<<1024, 512, 0, stream>>>(Up, VTD, fdP, w1dT, w2T,
                                         eb2 + l*512, aggP);
        k_node1<<<512, 256, 0, stream>>>(nfP, aggP, nw1T, nb1 + l*512, h1P);
        k_node2<<<512, 256, 0, stream>>>(nf, h1P, nw2T, nb2 + l*512, nfP);
    }
    k_coord<<<64, 256, 0, stream>>>(nf, cW, out);
    k_graph<<<64, 256, 0, stream>>>(nf, lW, lat, out);
}

// Round 14
// 354.252 us; speedup vs baseline: 1.7627x; 1.0031x over previous
//
#include <hip/hip_runtime.h>
#include <math.h>

// B=64 graphs, A=32 atoms, N=2048 nodes, E=65536 edges, H=512, LAT=256, L=4, DIS=60, EIN=1093
// Weights in MFMA B-fragment order; activations (nfP,h1P,aggP) in A-fragment-packed bf16.
// Node-side GEMMs: LDS-free, 1024 blocks (4 waves/SIMD TLP — they are L2-latency-bound).
// fd sinusoid fragments precomputed once. V emitted in f32 D-layout.

typedef short bf16x8 __attribute__((ext_vector_type(8)));
typedef float f32x4 __attribute__((ext_vector_type(4)));

__device__ __forceinline__ float silu_f(float x) {
    float e = __builtin_amdgcn_exp2f(x * -1.44269504088896f);
    return x * __builtin_amdgcn_rcpf(1.0f + e);
}
__device__ __forceinline__ unsigned short f2bf(float x) {
    unsigned int u = __float_as_uint(x);
    u += 0x7fffu + ((u >> 16) & 1u);
    return (unsigned short)(u >> 16);
}
__device__ __forceinline__ unsigned int cvt_pk_bf16(float lo, float hi) {
    unsigned int r;
    asm("v_cvt_pk_bf16_f32 %0, %1, %2" : "=v"(r) : "v"(lo), "v"(hi));
    return r;
}
__device__ __forceinline__ size_t apack_idx(int ng, int m, int c) {
    return ((size_t)(ng*16 + (c >> 5))*64 + (m + 16*((c >> 3) & 3)))*8 + (c & 7);
}

// ---- workspace layout (float offsets) ----
#define NF_OFF    0
#define UP_OFF    (2048*512)
#define VTD_OFF   (2*2048*512)
#define NFP_OFF   (VTD_OFF + 1048576)
#define H1P_OFF   (NFP_OFF + 524288)
#define AGGP_OFF  (H1P_OFF + 524288)
#define WBF_OFF   (AGGP_OFF + 524288)
#define SZ_INITT (512*768)
#define SZ_UVT   (1024*512)
#define SZ_W1DT  (512*64)
#define SZ_W2T   (512*512)
#define SZ_NW1T  (512*1024)
#define SZ_NW2T  (512*512)
#define SZ_LAYER (SZ_UVT+SZ_W1DT+SZ_W2T+SZ_NW1T+SZ_NW2T)
#define WBF_FLOATS ((SZ_INITT + 4*SZ_LAYER + 1)/2)
#define FDP_OFF   (WBF_OFF + WBF_FLOATS)

// ---- weight transpose+convert+fragment-pack ----
__global__ __launch_bounds__(256) void k_prep(
    const float* __restrict__ Wl, const float* __restrict__ eW1,
    const float* __restrict__ eW2, const float* __restrict__ nW1,
    const float* __restrict__ nW2, unsigned short* __restrict__ wbf)
{
    __shared__ float tile[32][33];
    int bid = blockIdx.x;
    const float* src; int K; unsigned short* dst; int t;
    if (bid < 384) { src = Wl; K = 768; dst = wbf; t = bid; }
    else {
        int b = bid - 384; int l = b / 1568; int j = b - l * 1568;
        const float* e1 = eW1 + (size_t)l * 1093 * 512;
        unsigned short* base = wbf + SZ_INITT + (size_t)l * SZ_LAYER;
        if (j < 256)      { src = e1;                       K = 512;  dst = base;                                   t = j; }
        else if (j < 512) { src = e1 + 512*512;             K = 512;  dst = base + 512*512;                         t = j-256; }
        else if (j < 544) { src = e1 + 1033*512;            K = 60;   dst = base + SZ_UVT;                          t = j-512; }
        else if (j < 800) { src = eW2 + (size_t)l*512*512;  K = 512;  dst = base + SZ_UVT+SZ_W1DT;                  t = j-544; }
        else if (j <1312) { src = nW1 + (size_t)l*1024*512; K = 1024; dst = base + SZ_UVT+SZ_W1DT+SZ_W2T;           t = j-800; }
        else              { src = nW2 + (size_t)l*512*512;  K = 512;  dst = base + SZ_UVT+SZ_W1DT+SZ_W2T+SZ_NW1T;   t = j-1312; }
    }
    int tr = t >> 4, tc = t & 15;
    int k0 = tr * 32, nn0 = tc * 32;
    {
        int r8 = threadIdx.x >> 5, cc = threadIdx.x & 31;
        #pragma unroll
        for (int rr = 0; rr < 4; ++rr) {
            int row = rr*8 + r8;
            int k = k0 + row;
            tile[row][cc] = (k < K) ? src[(size_t)k*512 + nn0 + cc] : 0.f;
        }
    }
    __syncthreads();
    int nt_loc = threadIdx.x >> 7;
    int l = (threadIdx.x >> 1) & 63;
    int jh = threadIdx.x & 1;
    int lj = l & 15, lh = l >> 4;
    float v0 = tile[lh*8 + jh*4 + 0][nt_loc*16 + lj];
    float v1 = tile[lh*8 + jh*4 + 1][nt_loc*16 + lj];
    float v2 = tile[lh*8 + jh*4 + 2][nt_loc*16 + lj];
    float v3 = tile[lh*8 + jh*4 + 3][nt_loc*16 + lj];
    uint2 pk = { cvt_pk_bf16(v0, v1), cvt_pk_bf16(v2, v3) };
    *(uint2*)&dst[((size_t)(tr*32 + tc*2 + nt_loc)*64 + l)*8 + jh*4] = pk;
}

// fd sinusoid B-fragments
__global__ __launch_bounds__(64) void k_fd(const float* __restrict__ frac,
                                           unsigned short* __restrict__ fdP)
{
    int bid = blockIdx.x;
    int n0 = bid * 2, g = n0 >> 5;
    int l = threadIdx.x, lj = l & 15, lh = l >> 4;
    float di[2][2][3];
    #pragma unroll
    for (int h = 0; h < 2; ++h)
        #pragma unroll
        for (int dd = 0; dd < 2; ++dd) {
            int dstn = g*32 + dd*16 + lj;
            #pragma unroll
            for (int comp = 0; comp < 3; ++comp) {
                float d = frac[dstn*3 + comp] - frac[(n0+h)*3 + comp];
                d -= floorf(d);
                di[h][dd][comp] = d;
            }
        }
    #pragma unroll
    for (int kt = 0; kt < 2; ++kt)
        #pragma unroll
        for (int mt = 0; mt < 4; ++mt) {
            int h = mt >> 1, dd = mt & 1;
            unsigned int w[4];
            #pragma unroll
            for (int p = 0; p < 4; ++p) {
                float vv[2];
                #pragma unroll
                for (int e = 0; e < 2; ++e) {
                    int k = kt*32 + lh*8 + p*2 + e;
                    float val = 0.f;
                    if (k < 60) {
                        int isCos = k >= 30;
                        int dq = k - (isCos ? 30 : 0);
                        int comp = dq >= 20 ? 2 : (dq >= 10 ? 1 : 0);
                        int f = dq - comp*10;
                        float u = di[h][dd][comp] * (float)f;
                        u -= floorf(u);
                        val = isCos ? __builtin_amdgcn_cosf(u) : __builtin_amdgcn_sinf(u);
                    }
                    vv[e] = val;
                }
                w[p] = cvt_pk_bf16(vv[0], vv[1]);
            }
            uint4 pk = { w[0], w[1], w[2], w[3] };
            *(uint4*)&fdP[(((size_t)bid*8 + kt*4 + mt)*64 + l)*8] = pk;
        }
}

// nf0 = concat(emb,t)@Wl + bl : writes nf (f32) and nfP (A-packed bf16)
__global__ __launch_bounds__(256) void k_init(
    const float* __restrict__ tvec, const float* __restrict__ emb,
    const unsigned short* __restrict__ WT, const float* __restrict__ bl,
    const int* __restrict__ atom_types, float* __restrict__ nf,
    unsigned short* __restrict__ nfP)
{
    __shared__ __align__(16) unsigned short cat_s[16*768];
    int ng = blockIdx.x >> 1, half = blockIdx.x & 1;
    int n0 = ng * 16, tid = threadIdx.x;
    for (int idx = tid; idx < 16*192; idx += 256) {
        int m = idx / 192, q = idx - m * 192;
        int k4 = q * 4, n = n0 + m;
        float4 v;
        if (k4 < 512) v = *(const float4*)&emb[(size_t)(atom_types[n]-1)*512 + k4];
        else          v = *(const float4*)&tvec[(size_t)(n>>5)*256 + (k4-512)];
        uint2 pk = { cvt_pk_bf16(v.x, v.y), cvt_pk_bf16(v.z, v.w) };
        *(uint2*)&cat_s[m*768 + (k4 ^ ((m&7)<<3))] = pk;
    }
    __syncthreads();
    int w = tid >> 6, l = tid & 63, lj = l & 15, lh = l >> 4;
    f32x4 acc[4];
    #pragma unroll
    for (int nt = 0; nt < 4; ++nt) acc[nt] = (f32x4){0.f,0.f,0.f,0.f};
    for (int kt = 0; kt < 24; ++kt) {
        int k = kt*32 + lh*8;
        bf16x8 a = *(const bf16x8*)&cat_s[lj*768 + (k ^ ((lj&7)<<3))];
        #pragma unroll
        for (int nt = 0; nt < 4; ++nt) {
            bf16x8 b = *(const bf16x8*)&WT[(((size_t)kt*32 + half*16 + w*4 + nt)*64 + l)*8];
            acc[nt] = __builtin_amdgcn_mfma_f32_16x16x32_bf16(a, b, acc[nt], 0, 0, 0);
        }
    }
    #pragma unroll
    for (int nt = 0; nt < 4; ++nt) {
        int c = half*256 + w*64 + nt*16 + lj;
        float bv = bl[c];
        #pragma unroll
        for (int r = 0; r < 4; ++r) {
            int m = lh*4 + r;
            float v = acc[nt][r] + bv;
            nf[(size_t)(n0 + m)*512 + c] = v;
            nfP[apack_idx(ng, m, c)] = f2bf(v);
        }
    }
}

// LDS-free uv: 1024 blocks (ng 128, half 2, chq 4), nt=2.
// half0: U' = nf@W1a + latip@W1c + b1; half1: VTD f32 D-layout per graph
__global__ __launch_bounds__(256) void k_uv(
    const unsigned short* __restrict__ nfP, const unsigned short* __restrict__ WT,
    const float* __restrict__ lat, const float* __restrict__ W1c,
    const float* __restrict__ b1, float* __restrict__ Up,
    float* __restrict__ VTD)
{
    int ng = blockIdx.x >> 3, half = (blockIdx.x >> 2) & 1, chq = blockIdx.x & 3;
    int n0 = ng * 16, g = n0 >> 5, tid = threadIdx.x;
    int w = tid >> 6, l = tid & 63, lj = l & 15, lh = l >> 4;
    const unsigned short* Wh = WT + (size_t)half*512*512;
    f32x4 acc[2];
    acc[0] = (f32x4){0.f,0.f,0.f,0.f};
    acc[1] = (f32x4){0.f,0.f,0.f,0.f};
    bf16x8 acur, anxt, bcur[2], bnxt[2];
    acur = *(const bf16x8*)&nfP[((size_t)(ng*16 + 0)*64 + l)*8];
    #pragma unroll
    for (int nt = 0; nt < 2; ++nt)
        bcur[nt] = *(const bf16x8*)&Wh[(((size_t)0*32 + chq*8 + w*2 + nt)*64 + l)*8];
    for (int kt = 0; kt < 16; ++kt) {
        if (kt < 15) {
            anxt = *(const bf16x8*)&nfP[((size_t)(ng*16 + kt + 1)*64 + l)*8];
            #pragma unroll
            for (int nt = 0; nt < 2; ++nt)
                bnxt[nt] = *(const bf16x8*)&Wh[(((size_t)(kt+1)*32 + chq*8 + w*2 + nt)*64 + l)*8];
        }
        #pragma unroll
        for (int nt = 0; nt < 2; ++nt)
            acc[nt] = __builtin_amdgcn_mfma_f32_16x16x32_bf16(acur, bcur[nt], acc[nt], 0, 0, 0);
        acur = anxt;
        #pragma unroll
        for (int nt = 0; nt < 2; ++nt) bcur[nt] = bnxt[nt];
    }
    if (half == 0) {
        float L[9], lip[9];
        #pragma unroll
        for (int i = 0; i < 9; ++i) L[i] = lat[g*9 + i];
        #pragma unroll
        for (int i = 0; i < 3; ++i)
            #pragma unroll
            for (int kk = 0; kk < 3; ++kk)
                lip[i*3+kk] = L[i*3]*L[kk*3] + L[i*3+1]*L[kk*3+1] + L[i*3+2]*L[kk*3+2];
        #pragma unroll
        for (int nt = 0; nt < 2; ++nt) {
            int c = chq*128 + w*32 + nt*16 + lj;
            float p3 = b1[c];
            #pragma unroll
            for (int t9 = 0; t9 < 9; ++t9) p3 += lip[t9] * W1c[t9*512 + c];
            #pragma unroll
            for (int r = 0; r < 4; ++r)
                Up[(size_t)(n0 + lh*4 + r)*512 + c] = acc[nt][r] + p3;
        }
    } else {
        int dd = (n0 & 31) >> 4;
        #pragma unroll
        for (int nt = 0; nt < 2; ++nt) {
            int ct = chq*8 + w*2 + nt;
            #pragma unroll
            for (int rr = 0; rr < 4; ++rr)
                VTD[(size_t)g*16384 + ct*512 + dd*256 + (lh*4+rr)*16 + lj] = acc[nt][rr];
        }
    }
}

// fused edge pipeline: 2 src nodes/block (M=64), 512 threads (8 waves), grid 1024.
__global__ __launch_bounds__(512) void k_edge(
    const float* __restrict__ Up, const float* __restrict__ VTD,
    const unsigned short* __restrict__ fdP,
    const unsigned short* __restrict__ W1dT,
    const unsigned short* __restrict__ W2T, const float* __restrict__ b2,
    unsigned short* __restrict__ aggP)
{
    __shared__ __align__(16) unsigned short ef1_s[64*512];
    int n0 = blockIdx.x * 2, g = n0 >> 5, tid = threadIdx.x;
    int wid = tid >> 6, l = tid & 63, lj = l & 15, lh = l >> 4;

    // ---------------- stage 1 ----------------
    {
        bf16x8 fdf[2][4];
        #pragma unroll
        for (int kt = 0; kt < 2; ++kt)
            #pragma unroll
            for (int mt = 0; mt < 4; ++mt)
                fdf[kt][mt] = *(const bf16x8*)&fdP[(((size_t)blockIdx.x*8 + kt*4 + mt)*64 + l)*8];

        #pragma unroll
        for (int q = 0; q < 4; ++q) {
            int ct = wid*4 + q;
            f32x4 a1[4];
            #pragma unroll
            for (int mt = 0; mt < 4; ++mt)
                a1[mt] = *(const f32x4*)&VTD[(size_t)g*16384 + ct*512 + (mt&1)*256 + lj*16 + lh*4];
            #pragma unroll
            for (int kt = 0; kt < 2; ++kt) {
                bf16x8 wf = *(const bf16x8*)&W1dT[(((size_t)kt*32 + ct)*64 + l)*8];
                #pragma unroll
                for (int mt = 0; mt < 4; ++mt)
                    a1[mt] = __builtin_amdgcn_mfma_f32_16x16x32_bf16(wf, fdf[kt][mt], a1[mt], 0, 0, 0);
            }
            int c0 = wid*64 + q*16 + lh*4;
            float4 bs0 = *(const float4*)&Up[(size_t)n0*512 + c0];
            float4 bs1 = *(const float4*)&Up[(size_t)(n0+1)*512 + c0];
            #pragma unroll
            for (int mt = 0; mt < 4; ++mt) {
                float4 bb = (mt >> 1) ? bs1 : bs0;
                int m = mt*16 + lj;
                float x0 = silu_f(a1[mt][0] + bb.x);
                float x1 = silu_f(a1[mt][1] + bb.y);
                float x2 = silu_f(a1[mt][2] + bb.z);
                float x3 = silu_f(a1[mt][3] + bb.w);
                uint2 pk = { cvt_pk_bf16(x0, x1), cvt_pk_bf16(x2, x3) };
                *(uint2*)&ef1_s[m*512 + (c0 ^ ((m&7)<<3))] = pk;
            }
        }
    }
    __syncthreads();

    // ---------------- stage 2 (barrier-free; A and B 1-deep prefetch) ----------------
    f32x4 acc2[4][4];
    #pragma unroll
    for (int mt = 0; mt < 4; ++mt)
        #pragma unroll
        for (int nt = 0; nt < 4; ++nt) acc2[mt][nt] = (f32x4){0.f,0.f,0.f,0.f};

    bf16x8 bcur[4], bnxt[4], afc[4], afn[4];
    #pragma unroll
    for (int nt = 0; nt < 4; ++nt)
        bcur[nt] = *(const bf16x8*)&W2T[(((size_t)0*32 + wid*4 + nt)*64 + l)*8];
    #pragma unroll
    for (int mt = 0; mt < 4; ++mt) {
        int m = mt*16 + lj;
        afc[mt] = *(const bf16x8*)&ef1_s[m*512 + ((lh*8) ^ ((m&7)<<3))];
    }

    for (int kt = 0; kt < 16; ++kt) {
        if (kt < 15) {
            int kn = (kt+1)*32 + lh*8;
            #pragma unroll
            for (int mt = 0; mt < 4; ++mt) {
                int m = mt*16 + lj;
                afn[mt] = *(const bf16x8*)&ef1_s[m*512 + (kn ^ ((m&7)<<3))];
            }
            #pragma unroll
            for (int nt = 0; nt < 4; ++nt)
                bnxt[nt] = *(const bf16x8*)&W2T[(((size_t)(kt+1)*32 + wid*4 + nt)*64 + l)*8];
        }
        __builtin_amdgcn_s_setprio(1);
        #pragma unroll
        for (int nt = 0; nt < 4; ++nt) {
            #pragma unroll
            for (int mt = 0; mt < 4; ++mt)
                acc2[mt][nt] = __builtin_amdgcn_mfma_f32_16x16x32_bf16(afc[mt], bcur[nt], acc2[mt][nt], 0, 0, 0);
        }
        __builtin_amdgcn_s_setprio(0);
        #pragma unroll
        for (int mt = 0; mt < 4; ++mt) afc[mt] = afn[mt];
        #pragma unroll
        for (int nt = 0; nt < 4; ++nt) bcur[nt] = bnxt[nt];
    }

    // epilogue: silu + per-node column mean -> aggP (A-packed bf16)
    int ngg = n0 >> 4, m0 = n0 & 15;
    #pragma unroll
    for (int nt = 0; nt < 4; ++nt) {
        int cc = wid*64 + nt*16 + lj;
        float bv = b2[cc];
        float s0 = 0.f, s1 = 0.f;
        #pragma unroll
        for (int mt = 0; mt < 4; ++mt)
            #pragma unroll
            for (int r = 0; r < 4; ++r) {
                float x = silu_f(acc2[mt][nt][r] + bv);
                if (mt < 2) s0 += x; else s1 += x;
            }
        s0 += __shfl_xor(s0, 16); s0 += __shfl_xor(s0, 32);
        s1 += __shfl_xor(s1, 16); s1 += __shfl_xor(s1, 32);
        if (lh == 0) {
            aggP[apack_idx(ngg, m0,     cc)] = f2bf(s0 * (1.0f/32.0f));
            aggP[apack_idx(ngg, m0 + 1, cc)] = f2bf(s1 * (1.0f/32.0f));
        }
    }
}

// LDS-free node GEMM1: 1024 blocks (ng 128, cq 8), nt=1.
__global__ __launch_bounds__(256) void k_node1(
    const unsigned short* __restrict__ nfP, const unsigned short* __restrict__ aggP,
    const unsigned short* __restrict__ W1T, const float* __restrict__ b1,
    unsigned short* __restrict__ h1P)
{
    int ng = blockIdx.x >> 3, cq = blockIdx.x & 7, tid = threadIdx.x;
    int w = tid >> 6, l = tid & 63, lj = l & 15, lh = l >> 4;
    f32x4 acc = (f32x4){0.f,0.f,0.f,0.f};
    bf16x8 acur, anxt, bcur, bnxt;
    acur = *(const bf16x8*)&nfP[((size_t)(ng*16 + 0)*64 + l)*8];
    bcur = *(const bf16x8*)&W1T[(((size_t)0*32 + cq*4 + w)*64 + l)*8];
    for (int kt = 0; kt < 32; ++kt) {
        if (kt < 31) {
            int kn = kt + 1;
            anxt = (kn < 16)
                ? *(const bf16x8*)&nfP[((size_t)(ng*16 + kn)*64 + l)*8]
                : *(const bf16x8*)&aggP[((size_t)(ng*16 + kn - 16)*64 + l)*8];
            bnxt = *(const bf16x8*)&W1T[(((size_t)kn*32 + cq*4 + w)*64 + l)*8];
        }
        acc = __builtin_amdgcn_mfma_f32_16x16x32_bf16(acur, bcur, acc, 0, 0, 0);
        acur = anxt;
        bcur = bnxt;
    }
    int c = cq*64 + w*16 + lj;
    float bv = b1[c];
    #pragma unroll
    for (int r = 0; r < 4; ++r) {
        int m = lh*4 + r;
        h1P[apack_idx(ng, m, c)] = f2bf(silu_f(acc[r] + bv));
    }
}

// LDS-free node GEMM2: 1024 blocks (ng 128, cq 8), nt=1. nf += silu(h1P@nW2 + b2); writes nfP.
__global__ __launch_bounds__(256) void k_node2(
    float* __restrict__ nf, const unsigned short* __restrict__ h1P,
    const unsigned short* __restrict__ W2T, const float* __restrict__ b2,
    unsigned short* __restrict__ nfP)
{
    int ng = blockIdx.x >> 3, cq = blockIdx.x & 7, tid = threadIdx.x;
    int n0 = ng * 16;
    int w = tid >> 6, l = tid & 63, lj = l & 15, lh = l >> 4;
    f32x4 acc = (f32x4){0.f,0.f,0.f,0.f};
    bf16x8 acur, anxt, bcur, bnxt;
    acur = *(const bf16x8*)&h1P[((size_t)(ng*16 + 0)*64 + l)*8];
    bcur = *(const bf16x8*)&W2T[(((size_t)0*32 + cq*4 + w)*64 + l)*8];
    for (int kt = 0; kt < 16; ++kt) {
        if (kt < 15) {
            anxt = *(const bf16x8*)&h1P[((size_t)(ng*16 + kt + 1)*64 + l)*8];
            bnxt = *(const bf16x8*)&W2T[(((size_t)(kt+1)*32 + cq*4 + w)*64 + l)*8];
        }
        acc = __builtin_amdgcn_mfma_f32_16x16x32_bf16(acur, bcur, acc, 0, 0, 0);
        acur = anxt;
        bcur = bnxt;
    }
    int c = cq*64 + w*16 + lj;
    float bv = b2[c];
    #pragma unroll
    for (int r = 0; r < 4; ++r) {
        int m = lh*4 + r;
        size_t o = (size_t)(n0 + m)*512 + c;
        float v = nf[o] + silu_f(acc[r] + bv);
        nf[o] = v;
        nfP[apack_idx(ng, m, c)] = f2bf(v);
    }
}

// coord_out: 64 blocks x 256 thr
__global__ __launch_bounds__(256) void k_coord(const float* __restrict__ nf,
                                               const float* __restrict__ cW,
                                               float* __restrict__ out) {
    int b = blockIdx.x, t = threadIdx.x;
    int nl = t >> 3, s = t & 7;
    int n = b*32 + nl;
    const float* row = nf + (size_t)n*512 + s*64;
    float p0 = 0.f, p1 = 0.f, p2 = 0.f;
    #pragma unroll
    for (int k4 = 0; k4 < 64; k4 += 4) {
        float4 v = *(const float4*)&row[k4];
        int kg = s*64 + k4;
        p0 += v.x*cW[(kg+0)*3+0] + v.y*cW[(kg+1)*3+0] + v.z*cW[(kg+2)*3+0] + v.w*cW[(kg+3)*3+0];
        p1 += v.x*cW[(kg+0)*3+1] + v.y*cW[(kg+1)*3+1] + v.z*cW[(kg+2)*3+1] + v.w*cW[(kg+3)*3+1];
        p2 += v.x*cW[(kg+0)*3+2] + v.y*cW[(kg+1)*3+2] + v.z*cW[(kg+2)*3+2] + v.w*cW[(kg+3)*3+2];
    }
    p0 += __shfl_xor(p0, 1); p0 += __shfl_xor(p0, 2); p0 += __shfl_xor(p0, 4);
    p1 += __shfl_xor(p1, 1); p1 += __shfl_xor(p1, 2); p1 += __shfl_xor(p1, 4);
    p2 += __shfl_xor(p2, 1); p2 += __shfl_xor(p2, 2); p2 += __shfl_xor(p2, 4);
    if (s == 0) {
        out[576 + n*3 + 0] = p0;
        out[576 + n*3 + 1] = p1;
        out[576 + n*3 + 2] = p2;
    }
}

__global__ __launch_bounds__(256) void k_graph(const float* __restrict__ nf,
                                               const float* __restrict__ lW,
                                               const float* __restrict__ lat,
                                               float* __restrict__ out) {
    __shared__ float gf[512];
    __shared__ float lo9[9];
    int b = blockIdx.x, tid = threadIdx.x;
    float s0 = 0.f, s1 = 0.f;
    for (int r = 0; r < 32; ++r) {
        s0 += nf[(b * 32 + r) * 512 + tid];
        s1 += nf[(b * 32 + r) * 512 + tid + 256];
    }
    gf[tid]       = s0 * (1.f / 32.f);
    gf[tid + 256] = s1 * (1.f / 32.f);
    __syncthreads();
    if (tid < 9) {
        float s = 0.f;
        for (int k = 0; k < 512; ++k) s += gf[k] * lW[k * 9 + tid];
        lo9[tid] = s;
    }
    __syncthreads();
    if (tid < 9) {
        int i = tid / 3, kk = tid - (tid / 3) * 3;
        float s = lo9[i*3+0] * lat[b*9 + 0*3 + kk]
                + lo9[i*3+1] * lat[b*9 + 1*3 + kk]
                + lo9[i*3+2] * lat[b*9 + 2*3 + kk];
        out[b * 9 + tid] = s;
    }
}

extern "C" void kernel_launch(void* const* d_in, const int* in_sizes, int n_in,
                              void* d_out, int out_size, void* d_ws, size_t ws_size,
                              hipStream_t stream)
{
    const float* t    = (const float*)d_in[0];
    const float* frac = (const float*)d_in[1];
    const float* lat  = (const float*)d_in[2];
    const float* emb  = (const float*)d_in[3];
    const float* Wl   = (const float*)d_in[4];
    const float* bl   = (const float*)d_in[5];
    const float* eW1  = (const float*)d_in[6];
    const float* eb1  = (const float*)d_in[7];
    const float* eW2  = (const float*)d_in[8];
    const float* eb2  = (const float*)d_in[9];
    const float* nW1  = (const float*)d_in[10];
    const float* nb1  = (const float*)d_in[11];
    const float* nW2  = (const float*)d_in[12];
    const float* nb2  = (const float*)d_in[13];
    const float* cW   = (const float*)d_in[14];
    const float* lW   = (const float*)d_in[15];
    const int* atom_types = (const int*)d_in[16];

    float* out  = (float*)d_out;
    float* wsf  = (float*)d_ws;
    float* nf   = wsf + NF_OFF;
    float* Up   = wsf + UP_OFF;
    float* VTD  = wsf + VTD_OFF;
    unsigned short* nfP  = (unsigned short*)(wsf + NFP_OFF);
    unsigned short* h1P  = (unsigned short*)(wsf + H1P_OFF);
    unsigned short* aggP = (unsigned short*)(wsf + AGGP_OFF);
    unsigned short* wbf  = (unsigned short*)(wsf + WBF_OFF);
    unsigned short* fdP  = (unsigned short*)(wsf + FDP_OFF);

    k_prep<<<384 + 4*1568, 256, 0, stream>>>(Wl, eW1, eW2, nW1, nW2, wbf);
    k_fd<<<1024, 64, 0, stream>>>(frac, fdP);
    k_init<<<256, 256, 0, stream>>>(t, emb, wbf, bl, atom_types, nf, nfP);
    for (int l = 0; l < 4; ++l) {
        const unsigned short* base = wbf + SZ_INITT + (size_t)l * SZ_LAYER;
        const unsigned short* w1dT = base + SZ_UVT;
        const unsigned short* w2T  = w1dT + SZ_W1DT;
        const unsigned short* nw1T = w2T + SZ_W2T;
        const unsigned short* nw2T = nw1T + SZ_NW1T;
        k_uv<<<1024, 256, 0, stream>>>(nfP, base, lat,
                                       eW1 + (size_t)l*1093*512 + 1024*512,
                                       eb1 + l*512, Up, VTD);
        k_edge<<<1024, 512, 0, stream>>>(Up, VTD, fdP, w1dT, w2T,
                                         eb2 + l*512, aggP);
        k_node1<<<1024, 256, 0, stream>>>(nfP, aggP, nw1T, nb1 + l*512, h1P);
        k_node2<<<1024, 256, 0, stream>>>(nf, h1P, nw2T, nb2 + l*512, nfP);
    }
    k_coord<<<64, 256, 0, stream>>>(nf, cW, out);
    k_graph<<<64, 256, 0, stream>>>(nf, lW, lat, out);
}

// Round 15
// 349.156 us; speedup vs baseline: 1.7884x; 1.0146x over previous
//
#include <hip/hip_runtime.h>
#include <math.h>

// B=64 graphs, A=32 atoms, N=2048 nodes, E=65536 edges, H=512, LAT=256, L=4, DIS=60, EIN=1093
// Weights in MFMA B-fragment order; activations (nfP,h1P,aggP) in A-fragment-packed bf16.
// Node-side GEMMs: LDS-free, chunk-4 fully-unrolled software pipelines (latency-bound fix).
// fd sinusoid fragments precomputed once. V emitted in f32 D-layout.

typedef short bf16x8 __attribute__((ext_vector_type(8)));
typedef float f32x4 __attribute__((ext_vector_type(4)));

__device__ __forceinline__ float silu_f(float x) {
    float e = __builtin_amdgcn_exp2f(x * -1.44269504088896f);
    return x * __builtin_amdgcn_rcpf(1.0f + e);
}
__device__ __forceinline__ unsigned short f2bf(float x) {
    unsigned int u = __float_as_uint(x);
    u += 0x7fffu + ((u >> 16) & 1u);
    return (unsigned short)(u >> 16);
}
__device__ __forceinline__ unsigned int cvt_pk_bf16(float lo, float hi) {
    unsigned int r;
    asm("v_cvt_pk_bf16_f32 %0, %1, %2" : "=v"(r) : "v"(lo), "v"(hi));
    return r;
}
__device__ __forceinline__ size_t apack_idx(int ng, int m, int c) {
    return ((size_t)(ng*16 + (c >> 5))*64 + (m + 16*((c >> 3) & 3)))*8 + (c & 7);
}

// ---- workspace layout (float offsets) ----
#define NF_OFF    0
#define UP_OFF    (2048*512)
#define VTD_OFF   (2*2048*512)
#define NFP_OFF   (VTD_OFF + 1048576)
#define H1P_OFF   (NFP_OFF + 524288)
#define AGGP_OFF  (H1P_OFF + 524288)
#define WBF_OFF   (AGGP_OFF + 524288)
#define SZ_INITT (512*768)
#define SZ_UVT   (1024*512)
#define SZ_W1DT  (512*64)
#define SZ_W2T   (512*512)
#define SZ_NW1T  (512*1024)
#define SZ_NW2T  (512*512)
#define SZ_LAYER (SZ_UVT+SZ_W1DT+SZ_W2T+SZ_NW1T+SZ_NW2T)
#define WBF_FLOATS ((SZ_INITT + 4*SZ_LAYER + 1)/2)
#define FDP_OFF   (WBF_OFF + WBF_FLOATS)

// ---- weight transpose+convert+fragment-pack ----
__global__ __launch_bounds__(256) void k_prep(
    const float* __restrict__ Wl, const float* __restrict__ eW1,
    const float* __restrict__ eW2, const float* __restrict__ nW1,
    const float* __restrict__ nW2, unsigned short* __restrict__ wbf)
{
    __shared__ float tile[32][33];
    int bid = blockIdx.x;
    const float* src; int K; unsigned short* dst; int t;
    if (bid < 384) { src = Wl; K = 768; dst = wbf; t = bid; }
    else {
        int b = bid - 384; int l = b / 1568; int j = b - l * 1568;
        const float* e1 = eW1 + (size_t)l * 1093 * 512;
        unsigned short* base = wbf + SZ_INITT + (size_t)l * SZ_LAYER;
        if (j < 256)      { src = e1;                       K = 512;  dst = base;                                   t = j; }
        else if (j < 512) { src = e1 + 512*512;             K = 512;  dst = base + 512*512;                         t = j-256; }
        else if (j < 544) { src = e1 + 1033*512;            K = 60;   dst = base + SZ_UVT;                          t = j-512; }
        else if (j < 800) { src = eW2 + (size_t)l*512*512;  K = 512;  dst = base + SZ_UVT+SZ_W1DT;                  t = j-544; }
        else if (j <1312) { src = nW1 + (size_t)l*1024*512; K = 1024; dst = base + SZ_UVT+SZ_W1DT+SZ_W2T;           t = j-800; }
        else              { src = nW2 + (size_t)l*512*512;  K = 512;  dst = base + SZ_UVT+SZ_W1DT+SZ_W2T+SZ_NW1T;   t = j-1312; }
    }
    int tr = t >> 4, tc = t & 15;
    int k0 = tr * 32, nn0 = tc * 32;
    {
        int r8 = threadIdx.x >> 5, cc = threadIdx.x & 31;
        #pragma unroll
        for (int rr = 0; rr < 4; ++rr) {
            int row = rr*8 + r8;
            int k = k0 + row;
            tile[row][cc] = (k < K) ? src[(size_t)k*512 + nn0 + cc] : 0.f;
        }
    }
    __syncthreads();
    int nt_loc = threadIdx.x >> 7;
    int l = (threadIdx.x >> 1) & 63;
    int jh = threadIdx.x & 1;
    int lj = l & 15, lh = l >> 4;
    float v0 = tile[lh*8 + jh*4 + 0][nt_loc*16 + lj];
    float v1 = tile[lh*8 + jh*4 + 1][nt_loc*16 + lj];
    float v2 = tile[lh*8 + jh*4 + 2][nt_loc*16 + lj];
    float v3 = tile[lh*8 + jh*4 + 3][nt_loc*16 + lj];
    uint2 pk = { cvt_pk_bf16(v0, v1), cvt_pk_bf16(v2, v3) };
    *(uint2*)&dst[((size_t)(tr*32 + tc*2 + nt_loc)*64 + l)*8 + jh*4] = pk;
}

// fd sinusoid B-fragments
__global__ __launch_bounds__(64) void k_fd(const float* __restrict__ frac,
                                           unsigned short* __restrict__ fdP)
{
    int bid = blockIdx.x;
    int n0 = bid * 2, g = n0 >> 5;
    int l = threadIdx.x, lj = l & 15, lh = l >> 4;
    float di[2][2][3];
    #pragma unroll
    for (int h = 0; h < 2; ++h)
        #pragma unroll
        for (int dd = 0; dd < 2; ++dd) {
            int dstn = g*32 + dd*16 + lj;
            #pragma unroll
            for (int comp = 0; comp < 3; ++comp) {
                float d = frac[dstn*3 + comp] - frac[(n0+h)*3 + comp];
                d -= floorf(d);
                di[h][dd][comp] = d;
            }
        }
    #pragma unroll
    for (int kt = 0; kt < 2; ++kt)
        #pragma unroll
        for (int mt = 0; mt < 4; ++mt) {
            int h = mt >> 1, dd = mt & 1;
            unsigned int w[4];
            #pragma unroll
            for (int p = 0; p < 4; ++p) {
                float vv[2];
                #pragma unroll
                for (int e = 0; e < 2; ++e) {
                    int k = kt*32 + lh*8 + p*2 + e;
                    float val = 0.f;
                    if (k < 60) {
                        int isCos = k >= 30;
                        int dq = k - (isCos ? 30 : 0);
                        int comp = dq >= 20 ? 2 : (dq >= 10 ? 1 : 0);
                        int f = dq - comp*10;
                        float u = di[h][dd][comp] * (float)f;
                        u -= floorf(u);
                        val = isCos ? __builtin_amdgcn_cosf(u) : __builtin_amdgcn_sinf(u);
                    }
                    vv[e] = val;
                }
                w[p] = cvt_pk_bf16(vv[0], vv[1]);
            }
            uint4 pk = { w[0], w[1], w[2], w[3] };
            *(uint4*)&fdP[(((size_t)bid*8 + kt*4 + mt)*64 + l)*8] = pk;
        }
}

// nf0 = concat(emb,t)@Wl + bl : writes nf (f32) and nfP (A-packed bf16)
__global__ __launch_bounds__(256) void k_init(
    const float* __restrict__ tvec, const float* __restrict__ emb,
    const unsigned short* __restrict__ WT, const float* __restrict__ bl,
    const int* __restrict__ atom_types, float* __restrict__ nf,
    unsigned short* __restrict__ nfP)
{
    __shared__ __align__(16) unsigned short cat_s[16*768];
    int ng = blockIdx.x >> 1, half = blockIdx.x & 1;
    int n0 = ng * 16, tid = threadIdx.x;
    for (int idx = tid; idx < 16*192; idx += 256) {
        int m = idx / 192, q = idx - m * 192;
        int k4 = q * 4, n = n0 + m;
        float4 v;
        if (k4 < 512) v = *(const float4*)&emb[(size_t)(atom_types[n]-1)*512 + k4];
        else          v = *(const float4*)&tvec[(size_t)(n>>5)*256 + (k4-512)];
        uint2 pk = { cvt_pk_bf16(v.x, v.y), cvt_pk_bf16(v.z, v.w) };
        *(uint2*)&cat_s[m*768 + (k4 ^ ((m&7)<<3))] = pk;
    }
    __syncthreads();
    int w = tid >> 6, l = tid & 63, lj = l & 15, lh = l >> 4;
    f32x4 acc[4];
    #pragma unroll
    for (int nt = 0; nt < 4; ++nt) acc[nt] = (f32x4){0.f,0.f,0.f,0.f};
    for (int kt = 0; kt < 24; ++kt) {
        int k = kt*32 + lh*8;
        bf16x8 a = *(const bf16x8*)&cat_s[lj*768 + (k ^ ((lj&7)<<3))];
        #pragma unroll
        for (int nt = 0; nt < 4; ++nt) {
            bf16x8 b = *(const bf16x8*)&WT[(((size_t)kt*32 + half*16 + w*4 + nt)*64 + l)*8];
            acc[nt] = __builtin_amdgcn_mfma_f32_16x16x32_bf16(a, b, acc[nt], 0, 0, 0);
        }
    }
    #pragma unroll
    for (int nt = 0; nt < 4; ++nt) {
        int c = half*256 + w*64 + nt*16 + lj;
        float bv = bl[c];
        #pragma unroll
        for (int r = 0; r < 4; ++r) {
            int m = lh*4 + r;
            float v = acc[nt][r] + bv;
            nf[(size_t)(n0 + m)*512 + c] = v;
            nfP[apack_idx(ng, m, c)] = f2bf(v);
        }
    }
}

// LDS-free uv: 1024 blocks (ng 128, half 2, chq 4), nt=2, chunk-2 pipeline.
__global__ __launch_bounds__(256) void k_uv(
    const unsigned short* __restrict__ nfP, const unsigned short* __restrict__ WT,
    const float* __restrict__ lat, const float* __restrict__ W1c,
    const float* __restrict__ b1, float* __restrict__ Up,
    float* __restrict__ VTD)
{
    int ng = blockIdx.x >> 3, half = (blockIdx.x >> 2) & 1, chq = blockIdx.x & 3;
    int n0 = ng * 16, g = n0 >> 5, tid = threadIdx.x;
    int w = tid >> 6, l = tid & 63, lj = l & 15, lh = l >> 4;
    const unsigned short* Wh = WT + (size_t)half*512*512;
    f32x4 acc[2];
    acc[0] = (f32x4){0.f,0.f,0.f,0.f};
    acc[1] = (f32x4){0.f,0.f,0.f,0.f};
    bf16x8 aB[2][2], bB[2][2][2];
    #pragma unroll
    for (int j = 0; j < 2; ++j) {
        aB[0][j] = *(const bf16x8*)&nfP[((size_t)(ng*16 + j)*64 + l)*8];
        #pragma unroll
        for (int nt = 0; nt < 2; ++nt)
            bB[0][j][nt] = *(const bf16x8*)&Wh[(((size_t)j*32 + chq*8 + w*2 + nt)*64 + l)*8];
    }
    #pragma unroll
    for (int c = 0; c < 8; ++c) {
        const int cur = c & 1, nxt = cur ^ 1;
        if (c < 7) {
            #pragma unroll
            for (int j = 0; j < 2; ++j) {
                int kt = (c+1)*2 + j;
                aB[nxt][j] = *(const bf16x8*)&nfP[((size_t)(ng*16 + kt)*64 + l)*8];
                #pragma unroll
                for (int nt = 0; nt < 2; ++nt)
                    bB[nxt][j][nt] = *(const bf16x8*)&Wh[(((size_t)kt*32 + chq*8 + w*2 + nt)*64 + l)*8];
            }
        }
        #pragma unroll
        for (int j = 0; j < 2; ++j)
            #pragma unroll
            for (int nt = 0; nt < 2; ++nt)
                acc[nt] = __builtin_amdgcn_mfma_f32_16x16x32_bf16(aB[cur][j], bB[cur][j][nt], acc[nt], 0, 0, 0);
    }
    if (half == 0) {
        float L[9], lip[9];
        #pragma unroll
        for (int i = 0; i < 9; ++i) L[i] = lat[g*9 + i];
        #pragma unroll
        for (int i = 0; i < 3; ++i)
            #pragma unroll
            for (int kk = 0; kk < 3; ++kk)
                lip[i*3+kk] = L[i*3]*L[kk*3] + L[i*3+1]*L[kk*3+1] + L[i*3+2]*L[kk*3+2];
        #pragma unroll
        for (int nt = 0; nt < 2; ++nt) {
            int c = chq*128 + w*32 + nt*16 + lj;
            float p3 = b1[c];
            #pragma unroll
            for (int t9 = 0; t9 < 9; ++t9) p3 += lip[t9] * W1c[t9*512 + c];
            #pragma unroll
            for (int r = 0; r < 4; ++r)
                Up[(size_t)(n0 + lh*4 + r)*512 + c] = acc[nt][r] + p3;
        }
    } else {
        int dd = (n0 & 31) >> 4;
        #pragma unroll
        for (int nt = 0; nt < 2; ++nt) {
            int ct = chq*8 + w*2 + nt;
            #pragma unroll
            for (int rr = 0; rr < 4; ++rr)
                VTD[(size_t)g*16384 + ct*512 + dd*256 + (lh*4+rr)*16 + lj] = acc[nt][rr];
        }
    }
}

// fused edge pipeline: 2 src nodes/block (M=64), 512 threads (8 waves), grid 1024.
// r13 stage-2 form (B 1-deep prefetch, A from LDS just-in-time, setprio).
__global__ __launch_bounds__(512) void k_edge(
    const float* __restrict__ Up, const float* __restrict__ VTD,
    const unsigned short* __restrict__ fdP,
    const unsigned short* __restrict__ W1dT,
    const unsigned short* __restrict__ W2T, const float* __restrict__ b2,
    unsigned short* __restrict__ aggP)
{
    __shared__ __align__(16) unsigned short ef1_s[64*512];
    int n0 = blockIdx.x * 2, g = n0 >> 5, tid = threadIdx.x;
    int wid = tid >> 6, l = tid & 63, lj = l & 15, lh = l >> 4;

    // ---------------- stage 1 ----------------
    {
        bf16x8 fdf[2][4];
        #pragma unroll
        for (int kt = 0; kt < 2; ++kt)
            #pragma unroll
            for (int mt = 0; mt < 4; ++mt)
                fdf[kt][mt] = *(const bf16x8*)&fdP[(((size_t)blockIdx.x*8 + kt*4 + mt)*64 + l)*8];

        #pragma unroll
        for (int q = 0; q < 4; ++q) {
            int ct = wid*4 + q;
            f32x4 a1[4];
            #pragma unroll
            for (int mt = 0; mt < 4; ++mt)
                a1[mt] = *(const f32x4*)&VTD[(size_t)g*16384 + ct*512 + (mt&1)*256 + lj*16 + lh*4];
            #pragma unroll
            for (int kt = 0; kt < 2; ++kt) {
                bf16x8 wf = *(const bf16x8*)&W1dT[(((size_t)kt*32 + ct)*64 + l)*8];
                #pragma unroll
                for (int mt = 0; mt < 4; ++mt)
                    a1[mt] = __builtin_amdgcn_mfma_f32_16x16x32_bf16(wf, fdf[kt][mt], a1[mt], 0, 0, 0);
            }
            int c0 = wid*64 + q*16 + lh*4;
            float4 bs0 = *(const float4*)&Up[(size_t)n0*512 + c0];
            float4 bs1 = *(const float4*)&Up[(size_t)(n0+1)*512 + c0];
            #pragma unroll
            for (int mt = 0; mt < 4; ++mt) {
                float4 bb = (mt >> 1) ? bs1 : bs0;
                int m = mt*16 + lj;
                float x0 = silu_f(a1[mt][0] + bb.x);
                float x1 = silu_f(a1[mt][1] + bb.y);
                float x2 = silu_f(a1[mt][2] + bb.z);
                float x3 = silu_f(a1[mt][3] + bb.w);
                uint2 pk = { cvt_pk_bf16(x0, x1), cvt_pk_bf16(x2, x3) };
                *(uint2*)&ef1_s[m*512 + (c0 ^ ((m&7)<<3))] = pk;
            }
        }
    }
    __syncthreads();

    // ---------------- stage 2 (barrier-free, B software-pipelined) ----------------
    f32x4 acc2[4][4];
    #pragma unroll
    for (int mt = 0; mt < 4; ++mt)
        #pragma unroll
        for (int nt = 0; nt < 4; ++nt) acc2[mt][nt] = (f32x4){0.f,0.f,0.f,0.f};

    bf16x8 bcur[4], bnxt[4];
    #pragma unroll
    for (int nt = 0; nt < 4; ++nt)
        bcur[nt] = *(const bf16x8*)&W2T[(((size_t)0*32 + wid*4 + nt)*64 + l)*8];

    for (int kt = 0; kt < 16; ++kt) {
        int k = kt*32 + lh*8;
        bf16x8 af[4];
        #pragma unroll
        for (int mt = 0; mt < 4; ++mt) {
            int m = mt*16 + lj;
            af[mt] = *(const bf16x8*)&ef1_s[m*512 + (k ^ ((m&7)<<3))];
        }
        if (kt < 15) {
            #pragma unroll
            for (int nt = 0; nt < 4; ++nt)
                bnxt[nt] = *(const bf16x8*)&W2T[(((size_t)(kt+1)*32 + wid*4 + nt)*64 + l)*8];
        }
        __builtin_amdgcn_s_setprio(1);
        #pragma unroll
        for (int nt = 0; nt < 4; ++nt) {
            #pragma unroll
            for (int mt = 0; mt < 4; ++mt)
                acc2[mt][nt] = __builtin_amdgcn_mfma_f32_16x16x32_bf16(af[mt], bcur[nt], acc2[mt][nt], 0, 0, 0);
        }
        __builtin_amdgcn_s_setprio(0);
        #pragma unroll
        for (int nt = 0; nt < 4; ++nt) bcur[nt] = bnxt[nt];
    }

    // epilogue: silu + per-node column mean -> aggP (A-packed bf16)
    int ngg = n0 >> 4, m0 = n0 & 15;
    #pragma unroll
    for (int nt = 0; nt < 4; ++nt) {
        int cc = wid*64 + nt*16 + lj;
        float bv = b2[cc];
        float s0 = 0.f, s1 = 0.f;
        #pragma unroll
        for (int mt = 0; mt < 4; ++mt)
            #pragma unroll
            for (int r = 0; r < 4; ++r) {
                float x = silu_f(acc2[mt][nt][r] + bv);
                if (mt < 2) s0 += x; else s1 += x;
            }
        s0 += __shfl_xor(s0, 16); s0 += __shfl_xor(s0, 32);
        s1 += __shfl_xor(s1, 16); s1 += __shfl_xor(s1, 32);
        if (lh == 0) {
            aggP[apack_idx(ngg, m0,     cc)] = f2bf(s0 * (1.0f/32.0f));
            aggP[apack_idx(ngg, m0 + 1, cc)] = f2bf(s1 * (1.0f/32.0f));
        }
    }
}

// LDS-free node GEMM1: 1024 blocks (ng 128, cq 8), nt=1, chunk-4 pipeline.
__global__ __launch_bounds__(256) void k_node1(
    const unsigned short* __restrict__ nfP, const unsigned short* __restrict__ aggP,
    const unsigned short* __restrict__ W1T, const float* __restrict__ b1,
    unsigned short* __restrict__ h1P)
{
    int ng = blockIdx.x >> 3, cq = blockIdx.x & 7, tid = threadIdx.x;
    int w = tid >> 6, l = tid & 63, lj = l & 15, lh = l >> 4;
    f32x4 acc = (f32x4){0.f,0.f,0.f,0.f};
    bf16x8 aB[2][4], bB[2][4];
    #pragma unroll
    for (int j = 0; j < 4; ++j) {
        aB[0][j] = *(const bf16x8*)&nfP[((size_t)(ng*16 + j)*64 + l)*8];
        bB[0][j] = *(const bf16x8*)&W1T[(((size_t)j*32 + cq*4 + w)*64 + l)*8];
    }
    #pragma unroll
    for (int c = 0; c < 8; ++c) {
        const int cur = c & 1, nxt = cur ^ 1;
        if (c < 7) {
            #pragma unroll
            for (int j = 0; j < 4; ++j) {
                int kt = (c+1)*4 + j;
                aB[nxt][j] = (kt < 16)
                    ? *(const bf16x8*)&nfP[((size_t)(ng*16 + kt)*64 + l)*8]
                    : *(const bf16x8*)&aggP[((size_t)(ng*16 + kt - 16)*64 + l)*8];
                bB[nxt][j] = *(const bf16x8*)&W1T[(((size_t)kt*32 + cq*4 + w)*64 + l)*8];
            }
        }
        #pragma unroll
        for (int j = 0; j < 4; ++j)
            acc = __builtin_amdgcn_mfma_f32_16x16x32_bf16(aB[cur][j], bB[cur][j], acc, 0, 0, 0);
    }
    int c = cq*64 + w*16 + lj;
    float bv = b1[c];
    #pragma unroll
    for (int r = 0; r < 4; ++r) {
        int m = lh*4 + r;
        h1P[apack_idx(ng, m, c)] = f2bf(silu_f(acc[r] + bv));
    }
}

// LDS-free node GEMM2: 1024 blocks (ng 128, cq 8), nt=1, chunk-4 pipeline.
__global__ __launch_bounds__(256) void k_node2(
    float* __restrict__ nf, const unsigned short* __restrict__ h1P,
    const unsigned short* __restrict__ W2T, const float* __restrict__ b2,
    unsigned short* __restrict__ nfP)
{
    int ng = blockIdx.x >> 3, cq = blockIdx.x & 7, tid = threadIdx.x;
    int n0 = ng * 16;
    int w = tid >> 6, l = tid & 63, lj = l & 15, lh = l >> 4;
    f32x4 acc = (f32x4){0.f,0.f,0.f,0.f};
    bf16x8 aB[2][4], bB[2][4];
    #pragma unroll
    for (int j = 0; j < 4; ++j) {
        aB[0][j] = *(const bf16x8*)&h1P[((size_t)(ng*16 + j)*64 + l)*8];
        bB[0][j] = *(const bf16x8*)&W2T[(((size_t)j*32 + cq*4 + w)*64 + l)*8];
    }
    #pragma unroll
    for (int c = 0; c < 4; ++c) {
        const int cur = c & 1, nxt = cur ^ 1;
        if (c < 3) {
            #pragma unroll
            for (int j = 0; j < 4; ++j) {
                int kt = (c+1)*4 + j;
                aB[nxt][j] = *(const bf16x8*)&h1P[((size_t)(ng*16 + kt)*64 + l)*8];
                bB[nxt][j] = *(const bf16x8*)&W2T[(((size_t)kt*32 + cq*4 + w)*64 + l)*8];
            }
        }
        #pragma unroll
        for (int j = 0; j < 4; ++j)
            acc = __builtin_amdgcn_mfma_f32_16x16x32_bf16(aB[cur][j], bB[cur][j], acc, 0, 0, 0);
    }
    int c = cq*64 + w*16 + lj;
    float bv = b2[c];
    #pragma unroll
    for (int r = 0; r < 4; ++r) {
        int m = lh*4 + r;
        size_t o = (size_t)(n0 + m)*512 + c;
        float v = nf[o] + silu_f(acc[r] + bv);
        nf[o] = v;
        nfP[apack_idx(ng, m, c)] = f2bf(v);
    }
}

// coord_out: 64 blocks x 256 thr
__global__ __launch_bounds__(256) void k_coord(const float* __restrict__ nf,
                                               const float* __restrict__ cW,
                                               float* __restrict__ out) {
    int b = blockIdx.x, t = threadIdx.x;
    int nl = t >> 3, s = t & 7;
    int n = b*32 + nl;
    const float* row = nf + (size_t)n*512 + s*64;
    float p0 = 0.f, p1 = 0.f, p2 = 0.f;
    #pragma unroll
    for (int k4 = 0; k4 < 64; k4 += 4) {
        float4 v = *(const float4*)&row[k4];
        int kg = s*64 + k4;
        p0 += v.x*cW[(kg+0)*3+0] + v.y*cW[(kg+1)*3+0] + v.z*cW[(kg+2)*3+0] + v.w*cW[(kg+3)*3+0];
        p1 += v.x*cW[(kg+0)*3+1] + v.y*cW[(kg+1)*3+1] + v.z*cW[(kg+2)*3+1] + v.w*cW[(kg+3)*3+1];
        p2 += v.x*cW[(kg+0)*3+2] + v.y*cW[(kg+1)*3+2] + v.z*cW[(kg+2)*3+2] + v.w*cW[(kg+3)*3+2];
    }
    p0 += __shfl_xor(p0, 1); p0 += __shfl_xor(p0, 2); p0 += __shfl_xor(p0, 4);
    p1 += __shfl_xor(p1, 1); p1 += __shfl_xor(p1, 2); p1 += __shfl_xor(p1, 4);
    p2 += __shfl_xor(p2, 1); p2 += __shfl_xor(p2, 2); p2 += __shfl_xor(p2, 4);
    if (s == 0) {
        out[576 + n*3 + 0] = p0;
        out[576 + n*3 + 1] = p1;
        out[576 + n*3 + 2] = p2;
    }
}

__global__ __launch_bounds__(256) void k_graph(const float* __restrict__ nf,
                                               const float* __restrict__ lW,
                                               const float* __restrict__ lat,
                                               float* __restrict__ out) {
    __shared__ float gf[512];
    __shared__ float lo9[9];
    int b = blockIdx.x, tid = threadIdx.x;
    float s0 = 0.f, s1 = 0.f;
    for (int r = 0; r < 32; ++r) {
        s0 += nf[(b * 32 + r) * 512 + tid];
        s1 += nf[(b * 32 + r) * 512 + tid + 256];
    }
    gf[tid]       = s0 * (1.f / 32.f);
    gf[tid + 256] = s1 * (1.f / 32.f);
    __syncthreads();
    if (tid < 9) {
        float s = 0.f;
        for (int k = 0; k < 512; ++k) s += gf[k] * lW[k * 9 + tid];
        lo9[tid] = s;
    }
    __syncthreads();
    if (tid < 9) {
        int i = tid / 3, kk = tid - (tid / 3) * 3;
        float s = lo9[i*3+0] * lat[b*9 + 0*3 + kk]
                + lo9[i*3+1] * lat[b*9 + 1*3 + kk]
                + lo9[i*3+2] * lat[b*9 + 2*3 + kk];
        out[b * 9 + tid] = s;
    }
}

extern "C" void kernel_launch(void* const* d_in, const int* in_sizes, int n_in,
                              void* d_out, int out_size, void* d_ws, size_t ws_size,
                              hipStream_t stream)
{
    const float* t    = (const float*)d_in[0];
    const float* frac = (const float*)d_in[1];
    const float* lat  = (const float*)d_in[2];
    const float* emb  = (const float*)d_in[3];
    const float* Wl   = (const float*)d_in[4];
    const float* bl   = (const float*)d_in[5];
    const float* eW1  = (const float*)d_in[6];
    const float* eb1  = (const float*)d_in[7];
    const float* eW2  = (const float*)d_in[8];
    const float* eb2  = (const float*)d_in[9];
    const float* nW1  = (const float*)d_in[10];
    const float* nb1  = (const float*)d_in[11];
    const float* nW2  = (const float*)d_in[12];
    const float* nb2  = (const float*)d_in[13];
    const float* cW   = (const float*)d_in[14];
    const float* lW   = (const float*)d_in[15];
    const int* atom_types = (const int*)d_in[16];

    float* out  = (float*)d_out;
    float* wsf  = (float*)d_ws;
    float* nf   = wsf + NF_OFF;
    float* Up   = wsf + UP_OFF;
    float* VTD  = wsf + VTD_OFF;
    unsigned short* nfP  = (unsigned short*)(wsf + NFP_OFF);
    unsigned short* h1P  = (unsigned short*)(wsf + H1P_OFF);
    unsigned short* aggP = (unsigned short*)(wsf + AGGP_OFF);
    unsigned short* wbf  = (unsigned short*)(wsf + WBF_OFF);
    unsigned short* fdP  = (unsigned short*)(wsf + FDP_OFF);

    k_prep<<<384 + 4*1568, 256, 0, stream>>>(Wl, eW1, eW2, nW1, nW2, wbf);
    k_fd<<<1024, 64, 0, stream>>>(frac, fdP);
    k_init<<<256, 256, 0, stream>>>(t, emb, wbf, bl, atom_types, nf, nfP);
    for (int l = 0; l < 4; ++l) {
        const unsigned short* base = wbf + SZ_INITT + (size_t)l * SZ_LAYER;
        const unsigned short* w1dT = base + SZ_UVT;
        const unsigned short* w2T  = w1dT + SZ_W1DT;
        const unsigned short* nw1T = w2T + SZ_W2T;
        const unsigned short* nw2T = nw1T + SZ_NW1T;
        k_uv<<<1024, 256, 0, stream>>>(nfP, base, lat,
                                       eW1 + (size_t)l*1093*512 + 1024*512,
                                       eb1 + l*512, Up, VTD);
        k_edge<<<1024, 512, 0, stream>>>(Up, VTD, fdP, w1dT, w2T,
                                         eb2 + l*512, aggP);
        k_node1<<<1024, 256, 0, stream>>>(nfP, aggP, nw1T, nb1 + l*512, h1P);
        k_node2<<<1024, 256, 0, stream>>>(nf, h1P, nw2T, nb2 + l*512, nfP);
    }
    k_coord<<<64, 256, 0, stream>>>(nf, cW, out);
    k_graph<<<64, 256, 0, stream>>>(nf, lW, lat, out);
}